// Round 1
// baseline (2855.321 us; speedup 1.0000x reference)
//
#include <hip/hip_runtime.h>
#include <math.h>

#define NH 12
#define HDIM 64
#define NTOK 197
#define EDIM 768
#define NB 64
#define MROWS (NB*NTOK)   // 12608

// ---------------------------------------------------------------------------
// Tiled f32 GEMM: C[M,768] = X[M,768] @ W[768,768]
// mode 0: scatter to [B, H, N, HD] layout (for q/k/v)
// mode 1: add bias, write row-major [M, 768] (final projection)
// Block: 256 threads, tile 64x64, K-step 16, each thread 4x4 micro-tile.
// M = 12608 = 197*64 exactly, so no bounds checks anywhere.
// ---------------------------------------------------------------------------
__global__ __launch_bounds__(256) void gemm_f32(
    const float* __restrict__ X, const float* __restrict__ W,
    float* __restrict__ out, const float* __restrict__ bias, int mode)
{
    __shared__ float As[16][64];   // transposed: As[k][m]
    __shared__ float Bs[16][64];   // Bs[k][n]

    const int t  = threadIdx.x;
    const int tx = t & 15, ty = t >> 4;
    const int m0 = blockIdx.y << 6, n0 = blockIdx.x << 6;
    const int ar = t >> 2,  ak = (t & 3)  << 2;   // A staging: row, k4
    const int br = t >> 4,  bc = (t & 15) << 2;   // B staging: k, col4

    float4 acc[4];
    acc[0] = make_float4(0.f,0.f,0.f,0.f);
    acc[1] = make_float4(0.f,0.f,0.f,0.f);
    acc[2] = make_float4(0.f,0.f,0.f,0.f);
    acc[3] = make_float4(0.f,0.f,0.f,0.f);

    for (int k0 = 0; k0 < EDIM; k0 += 16) {
        float4 av = *(const float4*)(X + (size_t)(m0 + ar) * EDIM + k0 + ak);
        float4 bv = *(const float4*)(W + (size_t)(k0 + br) * EDIM + n0 + bc);
        __syncthreads();   // protect previous iteration's reads
        As[ak+0][ar] = av.x; As[ak+1][ar] = av.y;
        As[ak+2][ar] = av.z; As[ak+3][ar] = av.w;
        *(float4*)&Bs[br][bc] = bv;
        __syncthreads();
#pragma unroll
        for (int kk = 0; kk < 16; ++kk) {
            float4 a = *(const float4*)&As[kk][ty << 2];
            float4 b = *(const float4*)&Bs[kk][tx << 2];
            acc[0].x += a.x*b.x; acc[0].y += a.x*b.y; acc[0].z += a.x*b.z; acc[0].w += a.x*b.w;
            acc[1].x += a.y*b.x; acc[1].y += a.y*b.y; acc[1].z += a.y*b.z; acc[1].w += a.y*b.w;
            acc[2].x += a.z*b.x; acc[2].y += a.z*b.y; acc[2].z += a.z*b.z; acc[2].w += a.z*b.w;
            acc[3].x += a.w*b.x; acc[3].y += a.w*b.y; acc[3].z += a.w*b.z; acc[3].w += a.w*b.w;
        }
    }

    if (mode == 0) {
        // col block n0 is 64-aligned -> head h == blockIdx.x, d = tx*4 + j
        const int h = blockIdx.x;
#pragma unroll
        for (int i2 = 0; i2 < 4; ++i2) {
            int row = m0 + (ty << 2) + i2;       // = b*197 + n
            int b   = row / NTOK;
            int n   = row - b * NTOK;
            float* dst = out + (((size_t)(b * NH + h) * NTOK + n) * HDIM + (tx << 2));
            *(float4*)dst = acc[i2];
        }
    } else {
        float4 bb = *(const float4*)(bias + n0 + (tx << 2));
#pragma unroll
        for (int i2 = 0; i2 < 4; ++i2) {
            int row = m0 + (ty << 2) + i2;
            float4 v = acc[i2];
            v.x += bb.x; v.y += bb.y; v.z += bb.z; v.w += bb.w;
            *(float4*)(out + (size_t)row * EDIM + n0 + (tx << 2)) = v;
        }
    }
}

// ---------------------------------------------------------------------------
// Fused rel-pos attention. One block per (b,h); 8 waves, each wave owns a
// query row i at a time. K,V and the four 30x64 rel-pos tables live in LDS.
// Rel-pos decomposition:
//   logit[i,j] = (q_i.k_j + Pv[iv(i,j)] + Ph[ih(i,j)]) * scale
//   out[i,d]  += sum_j a_j * (V[j,d] + rv_v[iv][d] + rv_h[ih][d])
// where Pv[t] = q_i . rk_v[t], Ph[t] = q_i . rk_h[t], t in [0,30).
// iv/ih: 0 if i==0 or j==0 (CLS), else grid-distance + 15.
// ---------------------------------------------------------------------------
__global__ __launch_bounds__(512) void attn_f32(
    const float* __restrict__ q_ws, const float* __restrict__ k_ws,
    const float* __restrict__ v_ws,
    const float* __restrict__ rkv, const float* __restrict__ rkh,
    const float* __restrict__ rvv, const float* __restrict__ rvh,
    float* __restrict__ o_ws)
{
    __shared__ float Ks[NTOK*HDIM];        // 50.4 KB
    __shared__ float Vs[NTOK*HDIM];        // 50.4 KB
    __shared__ float Tv[30*HDIM], Th[30*HDIM];   // rel-pos key tables
    __shared__ float Uv[30*HDIM], Uh[30*HDIM];   // rel-pos value tables
    __shared__ float qs[8][HDIM];
    __shared__ float Pv[8][32], Ph[8][32];
    __shared__ float arow[8][200];

    const int tid  = threadIdx.x;
    const int w    = tid >> 6, lane = tid & 63;
    const int bh   = blockIdx.x;
    const int b    = bh / NH, h = bh - b * NH;
    const float* Qp = q_ws + (size_t)bh * NTOK * HDIM;
    const float* Kp = k_ws + (size_t)bh * NTOK * HDIM;
    const float* Vp = v_ws + (size_t)bh * NTOK * HDIM;

    for (int idx = tid; idx < NTOK*HDIM/4; idx += 512) {
        ((float4*)Ks)[idx] = ((const float4*)Kp)[idx];
        ((float4*)Vs)[idx] = ((const float4*)Vp)[idx];
    }
    for (int idx = tid; idx < 30*HDIM/4; idx += 512) {
        ((float4*)Tv)[idx] = ((const float4*)rkv)[idx];
        ((float4*)Th)[idx] = ((const float4*)rkh)[idx];
        ((float4*)Uv)[idx] = ((const float4*)rvv)[idx];
        ((float4*)Uh)[idx] = ((const float4*)rvh)[idx];
    }
    __syncthreads();

    const float scale = 0.125f;
    for (int i = w; i < NTOK; i += 8) {
        qs[w][lane] = Qp[i * HDIM + lane];
        __builtin_amdgcn_wave_barrier();

        // Pv/Ph: lanes 0..29 -> Pv[t], lanes 32..61 -> Ph[t]
        {
            int tt = lane & 31;
            const float* tab = (lane < 32) ? Tv : Th;
            if (tt < 30) {
                float dot = 0.f;
#pragma unroll 8
                for (int dd = 0; dd < HDIM; ++dd) {
                    int d = (tt + dd) & 63;            // skew: avoid bank conflicts
                    dot += qs[w][d] * tab[tt * HDIM + d];
                }
                if (lane < 32) Pv[w][tt] = dot; else Ph[w][tt] = dot;
            }
        }
        __builtin_amdgcn_wave_barrier();

        int giv = 0, gih = 0;
        if (i > 0) { giv = (i - 1) / 14; gih = (i - 1) % 14; }

        float sreg[4];
        float mymax = -1e30f;
#pragma unroll
        for (int jj = 0; jj < 4; ++jj) {
            int j = (jj << 6) + lane;
            float sv = -1e30f;
            if (j < NTOK) {
                float dot = 0.f;
#pragma unroll 8
                for (int dd = 0; dd < HDIM; ++dd) {
                    int d = (lane + dd) & 63;          // skew
                    dot += qs[w][d] * Ks[j * HDIM + d];
                }
                int tv = 0, th = 0;
                if (i > 0 && j > 0) {
                    int gj = j - 1;
                    tv = gj / 14 - giv + 15;
                    th = gj % 14 - gih + 15;
                }
                sv = (dot + Pv[w][tv] + Ph[w][th]) * scale;
            }
            sreg[jj] = sv;
            mymax = fmaxf(mymax, sv);
        }
#pragma unroll
        for (int off = 32; off >= 1; off >>= 1)
            mymax = fmaxf(mymax, __shfl_xor(mymax, off));

        float sum = 0.f;
#pragma unroll
        for (int jj = 0; jj < 4; ++jj) {
            int j = (jj << 6) + lane;
            float p = (j < NTOK) ? __expf(sreg[jj] - mymax) : 0.f;
            sreg[jj] = p;
            sum += p;
        }
#pragma unroll
        for (int off = 32; off >= 1; off >>= 1)
            sum += __shfl_xor(sum, off);
        float inv = 1.f / sum;
#pragma unroll
        for (int jj = 0; jj < 4; ++jj) {
            int j = (jj << 6) + lane;
            if (j < NTOK) arow[w][j] = sreg[jj] * inv;
        }
        __builtin_amdgcn_wave_barrier();

        // PV + rel-pos value: lane owns output dim d
        float acc = 0.f;
        const int d = lane;
        for (int j = 0; j < NTOK; ++j) {
            float a = arow[w][j];
            int tv = 0, th = 0;
            if (i > 0 && j > 0) {
                int gj = j - 1;
                tv = gj / 14 - giv + 15;
                th = gj % 14 - gih + 15;
            }
            acc += a * (Vs[j * HDIM + d] + Uv[tv * HDIM + d] + Uh[th * HDIM + d]);
        }
        // write in [B, N, H*HD] layout for the projection GEMM
        o_ws[(((size_t)b * NTOK + i) * NH + h) * HDIM + d] = acc;
    }
}

extern "C" void kernel_launch(void* const* d_in, const int* in_sizes, int n_in,
                              void* d_out, int out_size, void* d_ws, size_t ws_size,
                              hipStream_t stream)
{
    const float* x     = (const float*)d_in[0];
    const float* wq    = (const float*)d_in[1];
    const float* wk    = (const float*)d_in[2];
    const float* wv    = (const float*)d_in[3];
    const float* wproj = (const float*)d_in[4];
    const float* bproj = (const float*)d_in[5];
    const float* rkv   = (const float*)d_in[6];
    const float* rkh   = (const float*)d_in[7];
    const float* rvv   = (const float*)d_in[8];
    const float* rvh   = (const float*)d_in[9];

    float* ws = (float*)d_ws;
    const size_t sz = (size_t)MROWS * EDIM;   // 9,682,944 floats
    float* q_ws = ws;
    float* k_ws = ws + sz;
    float* v_ws = ws + 2 * sz;
    float* o_ws = ws + 3 * sz;

    dim3 g(EDIM / 64, MROWS / 64);   // (12, 197)
    gemm_f32<<<g, 256, 0, stream>>>(x, wq, q_ws, nullptr, 0);
    gemm_f32<<<g, 256, 0, stream>>>(x, wk, k_ws, nullptr, 0);
    gemm_f32<<<g, 256, 0, stream>>>(x, wv, v_ws, nullptr, 0);
    attn_f32<<<NB * NH, 512, 0, stream>>>(q_ws, k_ws, v_ws,
                                          rkv, rkh, rvv, rvh, o_ws);
    gemm_f32<<<g, 256, 0, stream>>>(o_ws, wproj, (float*)d_out, bproj, 1);
}

// Round 3
// 1180.709 us; speedup vs baseline: 2.4183x; 2.4183x over previous
//
#include <hip/hip_runtime.h>
#include <math.h>

typedef _Float16 f16;
typedef __attribute__((ext_vector_type(8))) _Float16 f16x8;
typedef __attribute__((ext_vector_type(4))) _Float16 f16x4;
typedef __attribute__((ext_vector_type(4))) float f32x4;

#define NH 12
#define HDIM 64
#define NTOK 197
#define EDIM 768
#define NB 64
#define MROWS (NB*NTOK)   // 12608

// ---------------------------------------------------------------------------
// Tiled f32 GEMM (correctness anchor; replaced by MFMA in a later round).
// ---------------------------------------------------------------------------
__global__ __launch_bounds__(256) void gemm_f32(
    const float* __restrict__ X, const float* __restrict__ W,
    float* __restrict__ out, const float* __restrict__ bias, int mode)
{
    __shared__ float As[16][64];
    __shared__ float Bs[16][64];

    const int t  = threadIdx.x;
    const int tx = t & 15, ty = t >> 4;
    const int m0 = blockIdx.y << 6, n0 = blockIdx.x << 6;
    const int ar = t >> 2,  ak = (t & 3)  << 2;
    const int br = t >> 4,  bc = (t & 15) << 2;

    float4 acc[4];
    acc[0] = make_float4(0.f,0.f,0.f,0.f);
    acc[1] = make_float4(0.f,0.f,0.f,0.f);
    acc[2] = make_float4(0.f,0.f,0.f,0.f);
    acc[3] = make_float4(0.f,0.f,0.f,0.f);

    for (int k0 = 0; k0 < EDIM; k0 += 16) {
        float4 av = *(const float4*)(X + (size_t)(m0 + ar) * EDIM + k0 + ak);
        float4 bv = *(const float4*)(W + (size_t)(k0 + br) * EDIM + n0 + bc);
        __syncthreads();
        As[ak+0][ar] = av.x; As[ak+1][ar] = av.y;
        As[ak+2][ar] = av.z; As[ak+3][ar] = av.w;
        *(float4*)&Bs[br][bc] = bv;
        __syncthreads();
#pragma unroll
        for (int kk = 0; kk < 16; ++kk) {
            float4 a = *(const float4*)&As[kk][ty << 2];
            float4 b = *(const float4*)&Bs[kk][tx << 2];
            acc[0].x += a.x*b.x; acc[0].y += a.x*b.y; acc[0].z += a.x*b.z; acc[0].w += a.x*b.w;
            acc[1].x += a.y*b.x; acc[1].y += a.y*b.y; acc[1].z += a.y*b.z; acc[1].w += a.y*b.w;
            acc[2].x += a.z*b.x; acc[2].y += a.z*b.y; acc[2].z += a.z*b.z; acc[2].w += a.z*b.w;
            acc[3].x += a.w*b.x; acc[3].y += a.w*b.y; acc[3].z += a.w*b.z; acc[3].w += a.w*b.w;
        }
    }

    if (mode == 0) {
        const int h = blockIdx.x;
#pragma unroll
        for (int i2 = 0; i2 < 4; ++i2) {
            int row = m0 + (ty << 2) + i2;
            int b   = row / NTOK;
            int n   = row - b * NTOK;
            float* dst = out + (((size_t)(b * NH + h) * NTOK + n) * HDIM + (tx << 2));
            *(float4*)dst = acc[i2];
        }
    } else {
        float4 bb = *(const float4*)(bias + n0 + (tx << 2));
#pragma unroll
        for (int i2 = 0; i2 < 4; ++i2) {
            int row = m0 + (ty << 2) + i2;
            float4 v = acc[i2];
            v.x += bb.x; v.y += bb.y; v.z += bb.z; v.w += bb.w;
            *(float4*)(out + (size_t)row * EDIM + n0 + (tx << 2)) = v;
        }
    }
}

// ---------------------------------------------------------------------------
// MFMA fused attention. One block per (b,h), 4 waves, each wave owns 16-row
// Q tiles (13 tiles cover 208 >= 197 rows).
//
// LDS layout (f16 unless noted), padded strides for conflict-free b128 reads:
//   Kl[272][72] : rows 0-196 K, 197-207 zero, 208+t rk_v[t], 240+t rk_h[t]
//   Vt[64][296] : Vt[d][k]: k<197 V[k][d]; 208+t rv_v[t][d]; 238+t rv_h[t][d]
//   Gt[32][232] : Gt[g][j]=1 iff token j in v-group g (g<14);
//                 Gt[16+c][j]=1 iff token j in h-group c
//   Al[w][16][296]: A_ext row-tile (cols 0-207 probs, 208-271 S', 272-287 0)
//   WS[w][16][64] f32: P-values (pre-softmax), then S' scatter (post)
// ---------------------------------------------------------------------------
#define SKL 72
#define SVT 296
#define SAL 296
#define SGT 232

__device__ __forceinline__ void wfence() {
    asm volatile("s_waitcnt lgkmcnt(0)" ::: "memory");
    __builtin_amdgcn_sched_barrier(0);
    __builtin_amdgcn_wave_barrier();
}

__device__ __forceinline__ unsigned div14(unsigned n) { return (n * 4682u) >> 16; }  // exact for n<=206

__global__ __launch_bounds__(256) void attn_mfma(
    const float* __restrict__ q_ws, const float* __restrict__ k_ws,
    const float* __restrict__ v_ws,
    const float* __restrict__ rkv, const float* __restrict__ rkh,
    const float* __restrict__ rvv, const float* __restrict__ rvh,
    float* __restrict__ o_ws)
{
    __shared__ f16 Kl[272*SKL];     // 39168 B
    __shared__ f16 Vt[64*SVT];      // 37888 B
    __shared__ f16 Gt[32*SGT];      // 14848 B
    __shared__ f16 Al[4][16*SAL];   // 37888 B
    __shared__ float WS[4][16*64];  // 16384 B   (total 146176 B)

    const int tid = threadIdx.x;
    const int w = tid >> 6, l = tid & 63;
    const int lr = l & 15, lq = l >> 4;
    const int bh = blockIdx.x;
    const int b = bh / NH, h = bh - b * NH;
    const float* Qp = q_ws + (size_t)bh * NTOK * HDIM;
    const float* Kp = k_ws + (size_t)bh * NTOK * HDIM;
    const float* Vp = v_ws + (size_t)bh * NTOK * HDIM;

    // ---- stage K_ext ----
    for (int idx = tid; idx < 272*8; idx += 256) {
        int row = idx >> 3, q8 = (idx & 7) << 3;
        const float* src = nullptr;
        if (row < NTOK)                    src = Kp  + row * 64 + q8;
        else if (row >= 208 && row < 238)  src = rkv + (row - 208) * 64 + q8;
        else if (row >= 240 && row < 270)  src = rkh + (row - 240) * 64 + q8;
        f16x8 hv;
#pragma unroll
        for (int e = 0; e < 8; ++e) hv[e] = (f16)0.f;
        if (src) {
            float4 a = *(const float4*)src, c = *(const float4*)(src + 4);
            hv[0]=(f16)a.x; hv[1]=(f16)a.y; hv[2]=(f16)a.z; hv[3]=(f16)a.w;
            hv[4]=(f16)c.x; hv[5]=(f16)c.y; hv[6]=(f16)c.z; hv[7]=(f16)c.w;
        }
        *(f16x8*)&Kl[row * SKL + q8] = hv;
    }
    // ---- stage Vt (transposed V + rel-value tables) ----
    for (int idx = tid; idx < 288*16; idx += 256) {
        int k = idx >> 4, d4 = (idx & 15) << 2;
        float4 vv = make_float4(0.f,0.f,0.f,0.f);
        if (k < NTOK)                    vv = *(const float4*)(Vp  + k * 64 + d4);
        else if (k >= 208 && k < 238)    vv = *(const float4*)(rvv + (k - 208) * 64 + d4);
        else if (k >= 238 && k < 268)    vv = *(const float4*)(rvh + (k - 238) * 64 + d4);
        Vt[(d4+0)*SVT + k] = (f16)vv.x;
        Vt[(d4+1)*SVT + k] = (f16)vv.y;
        Vt[(d4+2)*SVT + k] = (f16)vv.z;
        Vt[(d4+3)*SVT + k] = (f16)vv.w;
    }
    // ---- stage Gt ----
    for (int idx = tid; idx < 32*SGT; idx += 256) {
        int r = idx / SGT, j = idx - r * SGT;
        f16 g = (f16)0.f;
        if (j >= 1 && j <= 196) {
            unsigned jd = div14(j - 1), jm = (j - 1) - jd * 14;
            if (r < 14 && (int)jd == r) g = (f16)1.f;
            else if (r >= 16 && r < 30 && (int)jm == r - 16) g = (f16)1.f;
        }
        Gt[idx] = g;
    }
    // ---- zero Al cols 208-287 (NaN fix: group-sum GEMM reads cols up to 223
    //      multiplied by zero Gt entries; 0 x garbage-Inf/NaN = NaN) ----
    for (int idx = tid; idx < 4*16*80; idx += 256) {
        int w2 = idx / (16*80), rem = idx - w2 * (16*80);
        int r = rem / 80, c = rem - r * 80;
        Al[w2][r * SAL + 208 + c] = (f16)0.f;
    }
    __syncthreads();

    // ---- per-wave row-tile loop ----
    for (int tt = w; tt < 13; tt += 4) {
        const int i0 = tt * 16;
        // Q fragments from global (A-operand layout: row=lr, k=lq*8+e)
        int qrow = i0 + lr; if (qrow > 196) qrow = 196;
        const float* qsrc = Qp + qrow * 64 + lq * 8;
        f16x8 qf[2];
#pragma unroll
        for (int kc = 0; kc < 2; ++kc) {
            float4 a = *(const float4*)(qsrc + kc * 32);
            float4 c = *(const float4*)(qsrc + kc * 32 + 4);
            qf[kc][0]=(f16)a.x; qf[kc][1]=(f16)a.y; qf[kc][2]=(f16)a.z; qf[kc][3]=(f16)a.w;
            qf[kc][4]=(f16)c.x; qf[kc][5]=(f16)c.y; qf[kc][6]=(f16)c.z; qf[kc][7]=(f16)c.w;
        }

        // ---- unified S|P GEMM: 17 col-tiles x 2 k-chunks ----
        f32x4 acc[17];
#pragma unroll
        for (int ct = 0; ct < 17; ++ct) {
            f32x4 a; a[0]=0.f; a[1]=0.f; a[2]=0.f; a[3]=0.f;
#pragma unroll
            for (int kc = 0; kc < 2; ++kc) {
                f16x8 bf = *(f16x8*)&Kl[(ct*16 + lr) * SKL + kc*32 + lq*8];
                a = __builtin_amdgcn_mfma_f32_16x16x32_f16(qf[kc], bf, a, 0, 0, 0);
            }
            acc[ct] = a;
        }

        // write P (tiles 13-16 -> WS cols 0-63)
#pragma unroll
        for (int ct = 13; ct < 17; ++ct)
#pragma unroll
            for (int rg = 0; rg < 4; ++rg)
                WS[w][(lq*4 + rg) * 64 + (ct-13)*16 + lr] = acc[ct][rg];
        wfence();

        // per-reg row info
        int giv[4], gih[4], irow[4];
#pragma unroll
        for (int rg = 0; rg < 4; ++rg) {
            int i = i0 + lq*4 + rg; irow[rg] = i;
            if (i == 0) { giv[rg] = -1000; gih[rg] = -1000; }
            else { unsigned gv = div14(i - 1); giv[rg] = (int)gv; gih[rg] = (i - 1) - (int)gv * 14; }
        }

        // ---- S epilogue: add rel-key gathers, scale, mask ----
#pragma unroll
        for (int ct = 0; ct < 13; ++ct) {
            int j = ct*16 + lr;
            unsigned jd = 0, jm = 0;
            if (j >= 1) { jd = div14(j - 1); jm = (j - 1) - jd * 14; }
            bool jcls = (j == 0), jpad = (j > 196);
#pragma unroll
            for (int rg = 0; rg < 4; ++rg) {
                int row = lq*4 + rg;
                int tv, th;
                if (irow[rg] == 0 || jcls) { tv = 0; th = 32; }
                else { tv = (int)jd - giv[rg] + 15; th = 32 + (int)jm - gih[rg] + 15; }
                float s = (acc[ct][rg] + WS[w][row*64 + tv] + WS[w][row*64 + th]) * 0.125f;
                if (jpad) s = -1e30f;
                acc[ct][rg] = s;
            }
        }

        // ---- softmax (rows live in 16-lane groups) ----
        float mx[4], sm[4];
#pragma unroll
        for (int rg = 0; rg < 4; ++rg) {
            float m = acc[0][rg];
#pragma unroll
            for (int ct = 1; ct < 13; ++ct) m = fmaxf(m, acc[ct][rg]);
            m = fmaxf(m, __shfl_xor(m, 1)); m = fmaxf(m, __shfl_xor(m, 2));
            m = fmaxf(m, __shfl_xor(m, 4)); m = fmaxf(m, __shfl_xor(m, 8));
            mx[rg] = m;
        }
#pragma unroll
        for (int rg = 0; rg < 4; ++rg) {
            float s = 0.f;
#pragma unroll
            for (int ct = 0; ct < 13; ++ct) {
                float p = __expf(acc[ct][rg] - mx[rg]);
                acc[ct][rg] = p; s += p;
            }
            s += __shfl_xor(s, 1); s += __shfl_xor(s, 2);
            s += __shfl_xor(s, 4); s += __shfl_xor(s, 8);
            sm[rg] = 1.f / s;
        }

        // ---- write A (cols 0-207) ----
        float a0v[4];
#pragma unroll
        for (int ct = 0; ct < 13; ++ct) {
            int j = ct*16 + lr;
#pragma unroll
            for (int rg = 0; rg < 4; ++rg) {
                float a = acc[ct][rg] * sm[rg];
                Al[w][(lq*4 + rg) * SAL + j] = (f16)a;
                if (ct == 0) a0v[rg] = a;   // col j = lr; only lanes lr==0 use it
            }
        }
        wfence();

        // ---- group-sum GEMM: [16x224] A @ Gt^T -> Sv (cols 0-15) | Sh (16-31)
        f32x4 gacc[2];
#pragma unroll
        for (int ct = 0; ct < 2; ++ct) { gacc[ct][0]=0.f; gacc[ct][1]=0.f; gacc[ct][2]=0.f; gacc[ct][3]=0.f; }
#pragma unroll
        for (int kc = 0; kc < 7; ++kc) {
            f16x8 af = *(f16x8*)&Al[w][lr * SAL + kc*32 + lq*8];
#pragma unroll
            for (int ct = 0; ct < 2; ++ct) {
                f16x8 bf = *(f16x8*)&Gt[(ct*16 + lr) * SGT + kc*32 + lq*8];
                gacc[ct] = __builtin_amdgcn_mfma_f32_16x16x32_f16(af, bf, gacc[ct], 0, 0, 0);
            }
        }

        // ---- zero WS, scatter S' ----
#pragma unroll
        for (int z = 0; z < 4; ++z) {
            f32x4 zz; zz[0]=0.f; zz[1]=0.f; zz[2]=0.f; zz[3]=0.f;
            *(f32x4*)&WS[w][z*256 + l*4] = zz;
        }
        wfence();
#pragma unroll
        for (int rg = 0; rg < 4; ++rg) {
            int row = lq*4 + rg;
            int g = lr;
            int tv, th;
            if (irow[rg] == 0) { tv = 0; th = 30; }
            else { tv = g - giv[rg] + 15; th = 30 + g - gih[rg] + 15; }
            atomicAdd(&WS[w][row*64 + tv], gacc[0][rg]);
            atomicAdd(&WS[w][row*64 + th], gacc[1][rg]);
        }
        if (lr == 0) {
#pragma unroll
            for (int rg = 0; rg < 4; ++rg) {
                int row = lq*4 + rg;
                atomicAdd(&WS[w][row*64 + 0],  a0v[rg]);
                atomicAdd(&WS[w][row*64 + 30], a0v[rg]);
            }
        }
        wfence();

        // ---- convert S' -> Al cols 208-271 ----
#pragma unroll
        for (int u = 0; u < 4; ++u) {
            int r = u*4 + lq, c = lr * 4;
            float4 f = *(float4*)&WS[w][r*64 + c];
            f16x4 hv; hv[0]=(f16)f.x; hv[1]=(f16)f.y; hv[2]=(f16)f.z; hv[3]=(f16)f.w;
            *(f16x4*)&Al[w][r * SAL + 208 + c] = hv;
        }
        wfence();

        // ---- PV GEMM: [16x288] A_ext @ V_ext -> O [16x64] ----
        f32x4 oacc[4];
#pragma unroll
        for (int ct = 0; ct < 4; ++ct) { oacc[ct][0]=0.f; oacc[ct][1]=0.f; oacc[ct][2]=0.f; oacc[ct][3]=0.f; }
#pragma unroll
        for (int kc = 0; kc < 9; ++kc) {
            f16x8 af = *(f16x8*)&Al[w][lr * SAL + kc*32 + lq*8];
#pragma unroll
            for (int ct = 0; ct < 4; ++ct) {
                f16x8 bf = *(f16x8*)&Vt[(ct*16 + lr) * SVT + kc*32 + lq*8];
                oacc[ct] = __builtin_amdgcn_mfma_f32_16x16x32_f16(af, bf, oacc[ct], 0, 0, 0);
            }
        }

        // ---- store O in [B, N, H*HD] layout ----
#pragma unroll
        for (int ct = 0; ct < 4; ++ct)
#pragma unroll
            for (int rg = 0; rg < 4; ++rg) {
                int i = i0 + lq*4 + rg;
                if (i < NTOK) {
                    int d = ct*16 + lr;
                    o_ws[((size_t)(b * NTOK + i) * NH + h) * HDIM + d] = oacc[ct][rg];
                }
            }
    }
}

extern "C" void kernel_launch(void* const* d_in, const int* in_sizes, int n_in,
                              void* d_out, int out_size, void* d_ws, size_t ws_size,
                              hipStream_t stream)
{
    const float* x     = (const float*)d_in[0];
    const float* wq    = (const float*)d_in[1];
    const float* wk    = (const float*)d_in[2];
    const float* wv    = (const float*)d_in[3];
    const float* wproj = (const float*)d_in[4];
    const float* bproj = (const float*)d_in[5];
    const float* rkv   = (const float*)d_in[6];
    const float* rkh   = (const float*)d_in[7];
    const float* rvv   = (const float*)d_in[8];
    const float* rvh   = (const float*)d_in[9];

    float* ws = (float*)d_ws;
    const size_t sz = (size_t)MROWS * EDIM;
    float* q_ws = ws;
    float* k_ws = ws + sz;
    float* v_ws = ws + 2 * sz;
    float* o_ws = ws + 3 * sz;

    dim3 g(EDIM / 64, MROWS / 64);
    gemm_f32<<<g, 256, 0, stream>>>(x, wq, q_ws, nullptr, 0);
    gemm_f32<<<g, 256, 0, stream>>>(x, wk, k_ws, nullptr, 0);
    gemm_f32<<<g, 256, 0, stream>>>(x, wv, v_ws, nullptr, 0);
    attn_mfma<<<NB * NH, 256, 0, stream>>>(q_ws, k_ws, v_ws,
                                           rkv, rkh, rvv, rvh, o_ws);
    gemm_f32<<<g, 256, 0, stream>>>(o_ws, wproj, (float*)d_out, bproj, 1);
}

// Round 4
// 257.648 us; speedup vs baseline: 11.0823x; 4.5826x over previous
//
#include <hip/hip_runtime.h>
#include <math.h>

typedef _Float16 f16;
typedef __attribute__((ext_vector_type(8))) _Float16 f16x8;
typedef __attribute__((ext_vector_type(4))) _Float16 f16x4;
typedef __attribute__((ext_vector_type(4))) float f32x4;

#define NH 12
#define HDIM 64
#define NTOK 197
#define EDIM 768
#define NB 64
#define MROWS (NB*NTOK)   // 12608

// ---------------------------------------------------------------------------
// x [12608x768] f32 -> f16.  4728 blocks x 256 thr x 8 elems = exact.
// ---------------------------------------------------------------------------
__global__ __launch_bounds__(256) void convert_x(
    const float* __restrict__ x, f16* __restrict__ xh)
{
    int idx = blockIdx.x * 256 + threadIdx.x;
    const float4* s = (const float4*)x + (size_t)idx * 2;
    float4 a = s[0], b = s[1];
    f16x8 h;
    h[0]=(f16)a.x; h[1]=(f16)a.y; h[2]=(f16)a.z; h[3]=(f16)a.w;
    h[4]=(f16)b.x; h[5]=(f16)b.y; h[6]=(f16)b.z; h[7]=(f16)b.w;
    *(f16x8*)(xh + (size_t)idx * 8) = h;
}

// ---------------------------------------------------------------------------
// Transpose + f16-ify weights: wT[n][k] = w[k][n].
// blockIdx.y = matrix (0=wq,1=wk,2=wv -> wqkvT rows m*768+n; 3=wproj -> wpT).
// ---------------------------------------------------------------------------
__global__ __launch_bounds__(256) void transpose_w(
    const float* __restrict__ wq, const float* __restrict__ wk,
    const float* __restrict__ wv, const float* __restrict__ wp,
    f16* __restrict__ wqkvT, f16* __restrict__ wpT)
{
    int m = blockIdx.y;
    const float* src = (m==0)?wq:(m==1)?wk:(m==2)?wv:wp;
    int idx = blockIdx.x * 256 + threadIdx.x;       // 73728 per matrix
    int n = idx / 96, kc = (idx - n * 96) * 8;
    f16x8 h;
#pragma unroll
    for (int e = 0; e < 8; ++e) h[e] = (f16)src[(size_t)(kc+e)*EDIM + n];
    f16* dst = (m < 3) ? (wqkvT + ((size_t)m*EDIM + n)*EDIM + kc)
                       : (wpT   + (size_t)n*EDIM + kc);
    *(f16x8*)dst = h;
}

// ---------------------------------------------------------------------------
// f16 MFMA GEMM:  C[M x N] = A[M x 768] @ Bt[N x 768]^T
// 128x128 tile, BK=64, 256 thr (4 waves, 2x2), wave owns 64x64 (4x4 16x16).
// LDS tiles XOR-swizzled (f16-idx ^= (row&7)<<3) on BOTH write & read (T2).
// Reg-staged with next-tile loads issued before compute (T14-lite).
// mode 0: scatter f16 to q/k/v [B,H,N,HD]; col block selects matrix.
// mode 1: f32 out[M x 768] + bias.
// ---------------------------------------------------------------------------
__global__ __launch_bounds__(256) void gemm_h(
    const f16* __restrict__ A, const f16* __restrict__ Bt,
    f16* __restrict__ q_o, f16* __restrict__ k_o, f16* __restrict__ v_o,
    float* __restrict__ p_o, const float* __restrict__ bias, int mode)
{
    __shared__ f16 As[128*64];   // 16 KB
    __shared__ f16 Bs[128*64];   // 16 KB

    const int tid = threadIdx.x;
    const int l  = tid & 63;
    const int w  = tid >> 6;
    const int lr = l & 15, lq = l >> 4;
    const int wr = w >> 1, wc = w & 1;
    const int m0 = blockIdx.y * 128, n0 = blockIdx.x * 128;

    // staging: thread t covers (per chunk p in 0..3) row p*32 + t/8, col (t&7)*8
    const int sr = tid >> 3, sc = (tid & 7) << 3;
    const int sw = (sr & 7) << 3;
    const int dsoff = sr * 64 + (sc ^ sw);          // f16 index, + p*2048

    const f16* agp[4]; const f16* bgp[4];
#pragma unroll
    for (int p = 0; p < 4; ++p) {
        int ra = m0 + p*32 + sr; if (ra >= MROWS) ra = MROWS - 1;
        agp[p] = A  + (size_t)ra * EDIM + sc;
        bgp[p] = Bt + (size_t)(n0 + p*32 + sr) * EDIM + sc;
    }

    f16x8 ar_[4], br_[4];
#pragma unroll
    for (int p = 0; p < 4; ++p) {
        ar_[p] = *(const f16x8*)agp[p];
        br_[p] = *(const f16x8*)bgp[p];
    }

    f32x4 acc[4][4];
#pragma unroll
    for (int mt = 0; mt < 4; ++mt)
#pragma unroll
        for (int nt = 0; nt < 4; ++nt) {
            acc[mt][nt][0]=0.f; acc[mt][nt][1]=0.f;
            acc[mt][nt][2]=0.f; acc[mt][nt][3]=0.f;
        }

    for (int kt = 0; kt < 12; ++kt) {
        __syncthreads();                 // previous compute finished
#pragma unroll
        for (int p = 0; p < 4; ++p) {
            *(f16x8*)&As[p*2048 + dsoff] = ar_[p];
            *(f16x8*)&Bs[p*2048 + dsoff] = br_[p];
        }
        if (kt < 11) {                   // issue next tile early (hide HBM lat)
            int ko = (kt + 1) * 64;
#pragma unroll
            for (int p = 0; p < 4; ++p) {
                ar_[p] = *(const f16x8*)(agp[p] + ko);
                br_[p] = *(const f16x8*)(bgp[p] + ko);
            }
        }
        __syncthreads();
#pragma unroll
        for (int ks = 0; ks < 2; ++ks) {
            const int kb = ks*32 + lq*8;
            f16x8 af[4], bf[4];
#pragma unroll
            for (int mt = 0; mt < 4; ++mt) {
                int Ra = wr*64 + mt*16 + lr;
                af[mt] = *(const f16x8*)&As[Ra*64 + (kb ^ ((Ra&7)<<3))];
                int Rb = wc*64 + mt*16 + lr;
                bf[mt] = *(const f16x8*)&Bs[Rb*64 + (kb ^ ((Rb&7)<<3))];
            }
#pragma unroll
            for (int mt = 0; mt < 4; ++mt)
#pragma unroll
                for (int nt = 0; nt < 4; ++nt)
                    acc[mt][nt] = __builtin_amdgcn_mfma_f32_16x16x32_f16(
                        af[mt], bf[nt], acc[mt][nt], 0, 0, 0);
        }
    }

    if (mode == 0) {
        const int mat   = n0 / EDIM;                 // block n-range within one matrix (768%128==0)
        const int hbase = ((n0 % EDIM) >> 6) + wc;   // head, uniform per wave-col
        f16* dst = (mat == 0) ? q_o : (mat == 1) ? k_o : v_o;
#pragma unroll
        for (int mt = 0; mt < 4; ++mt)
#pragma unroll
            for (int rg = 0; rg < 4; ++rg) {
                int R = m0 + wr*64 + mt*16 + lq*4 + rg;
                if (R < MROWS) {
                    int bb = R / NTOK, nn = R - bb * NTOK;
                    f16* base = dst + (((size_t)(bb*NH + hbase))*NTOK + nn) * HDIM;
#pragma unroll
                    for (int nt = 0; nt < 4; ++nt)
                        base[nt*16 + lr] = (f16)acc[mt][nt][rg];
                }
            }
    } else {
#pragma unroll
        for (int mt = 0; mt < 4; ++mt)
#pragma unroll
            for (int rg = 0; rg < 4; ++rg) {
                int R = m0 + wr*64 + mt*16 + lq*4 + rg;
                if (R < MROWS) {
                    float* base = p_o + (size_t)R * EDIM + n0 + wc*64;
#pragma unroll
                    for (int nt = 0; nt < 4; ++nt) {
                        int c = nt*16 + lr;
                        base[c] = acc[mt][nt][rg] + bias[n0 + wc*64 + c];
                    }
                }
            }
    }
}

// ---------------------------------------------------------------------------
// MFMA fused attention (f16 in / f16 out). Same structure as round 3.
// ---------------------------------------------------------------------------
#define SKL 72
#define SVT 296
#define SAL 296
#define SGT 232

__device__ __forceinline__ void wfence() {
    asm volatile("s_waitcnt lgkmcnt(0)" ::: "memory");
    __builtin_amdgcn_sched_barrier(0);
    __builtin_amdgcn_wave_barrier();
}

__device__ __forceinline__ unsigned div14(unsigned n) { return (n * 4682u) >> 16; }  // exact for n<=206

__global__ __launch_bounds__(256) void attn_mfma(
    const f16* __restrict__ q_ws, const f16* __restrict__ k_ws,
    const f16* __restrict__ v_ws,
    const float* __restrict__ rkv, const float* __restrict__ rkh,
    const float* __restrict__ rvv, const float* __restrict__ rvh,
    f16* __restrict__ o_ws)
{
    __shared__ f16 Kl[272*SKL];
    __shared__ f16 Vt[64*SVT];
    __shared__ f16 Gt[32*SGT];
    __shared__ f16 Al[4][16*SAL];
    __shared__ float WS[4][16*64];

    const int tid = threadIdx.x;
    const int w = tid >> 6, l = tid & 63;
    const int lr = l & 15, lq = l >> 4;
    const int bh = blockIdx.x;
    const int b = bh / NH, h = bh - b * NH;
    const f16* Qp = q_ws + (size_t)bh * NTOK * HDIM;
    const f16* Kp = k_ws + (size_t)bh * NTOK * HDIM;
    const f16* Vp = v_ws + (size_t)bh * NTOK * HDIM;

    // ---- stage K_ext ----
    for (int idx = tid; idx < 272*8; idx += 256) {
        int row = idx >> 3, q8 = (idx & 7) << 3;
        f16x8 hv;
#pragma unroll
        for (int e = 0; e < 8; ++e) hv[e] = (f16)0.f;
        if (row < NTOK) {
            hv = *(const f16x8*)(Kp + row * 64 + q8);
        } else if (row >= 208 && row < 238) {
            const float* src = rkv + (row - 208) * 64 + q8;
            float4 a = *(const float4*)src, c = *(const float4*)(src + 4);
            hv[0]=(f16)a.x; hv[1]=(f16)a.y; hv[2]=(f16)a.z; hv[3]=(f16)a.w;
            hv[4]=(f16)c.x; hv[5]=(f16)c.y; hv[6]=(f16)c.z; hv[7]=(f16)c.w;
        } else if (row >= 240 && row < 270) {
            const float* src = rkh + (row - 240) * 64 + q8;
            float4 a = *(const float4*)src, c = *(const float4*)(src + 4);
            hv[0]=(f16)a.x; hv[1]=(f16)a.y; hv[2]=(f16)a.z; hv[3]=(f16)a.w;
            hv[4]=(f16)c.x; hv[5]=(f16)c.y; hv[6]=(f16)c.z; hv[7]=(f16)c.w;
        }
        *(f16x8*)&Kl[row * SKL + q8] = hv;
    }
    // ---- stage Vt ----
    for (int idx = tid; idx < 288*16; idx += 256) {
        int k = idx >> 4, d4 = (idx & 15) << 2;
        f16x4 t;
        t[0]=(f16)0.f; t[1]=(f16)0.f; t[2]=(f16)0.f; t[3]=(f16)0.f;
        if (k < NTOK) {
            t = *(const f16x4*)(Vp + k * 64 + d4);
        } else if (k >= 208 && k < 238) {
            float4 vv = *(const float4*)(rvv + (k - 208) * 64 + d4);
            t[0]=(f16)vv.x; t[1]=(f16)vv.y; t[2]=(f16)vv.z; t[3]=(f16)vv.w;
        } else if (k >= 238 && k < 268) {
            float4 vv = *(const float4*)(rvh + (k - 238) * 64 + d4);
            t[0]=(f16)vv.x; t[1]=(f16)vv.y; t[2]=(f16)vv.z; t[3]=(f16)vv.w;
        }
        Vt[(d4+0)*SVT + k] = t[0];
        Vt[(d4+1)*SVT + k] = t[1];
        Vt[(d4+2)*SVT + k] = t[2];
        Vt[(d4+3)*SVT + k] = t[3];
    }
    // ---- stage Gt ----
    for (int idx = tid; idx < 32*SGT; idx += 256) {
        int r = idx / SGT, j = idx - r * SGT;
        f16 g = (f16)0.f;
        if (j >= 1 && j <= 196) {
            unsigned jd = div14(j - 1), jm = (j - 1) - jd * 14;
            if (r < 14 && (int)jd == r) g = (f16)1.f;
            else if (r >= 16 && r < 30 && (int)jm == r - 16) g = (f16)1.f;
        }
        Gt[idx] = g;
    }
    // ---- zero Al cols 208-287 ----
    for (int idx = tid; idx < 4*16*80; idx += 256) {
        int w2 = idx / (16*80), rem = idx - w2 * (16*80);
        int r = rem / 80, c = rem - r * 80;
        Al[w2][r * SAL + 208 + c] = (f16)0.f;
    }
    __syncthreads();

    for (int tt = w; tt < 13; tt += 4) {
        const int i0 = tt * 16;
        int qrow = i0 + lr; if (qrow > 196) qrow = 196;
        const f16* qsrc = Qp + qrow * 64 + lq * 8;
        f16x8 qf[2];
        qf[0] = *(const f16x8*)qsrc;
        qf[1] = *(const f16x8*)(qsrc + 32);

        // ---- unified S|P GEMM ----
        f32x4 acc[17];
#pragma unroll
        for (int ct = 0; ct < 17; ++ct) {
            f32x4 a; a[0]=0.f; a[1]=0.f; a[2]=0.f; a[3]=0.f;
#pragma unroll
            for (int kc = 0; kc < 2; ++kc) {
                f16x8 bf = *(f16x8*)&Kl[(ct*16 + lr) * SKL + kc*32 + lq*8];
                a = __builtin_amdgcn_mfma_f32_16x16x32_f16(qf[kc], bf, a, 0, 0, 0);
            }
            acc[ct] = a;
        }

#pragma unroll
        for (int ct = 13; ct < 17; ++ct)
#pragma unroll
            for (int rg = 0; rg < 4; ++rg)
                WS[w][(lq*4 + rg) * 64 + (ct-13)*16 + lr] = acc[ct][rg];
        wfence();

        int giv[4], gih[4], irow[4];
#pragma unroll
        for (int rg = 0; rg < 4; ++rg) {
            int i = i0 + lq*4 + rg; irow[rg] = i;
            if (i == 0) { giv[rg] = -1000; gih[rg] = -1000; }
            else { unsigned gv = div14(i - 1); giv[rg] = (int)gv; gih[rg] = (i - 1) - (int)gv * 14; }
        }

#pragma unroll
        for (int ct = 0; ct < 13; ++ct) {
            int j = ct*16 + lr;
            unsigned jd = 0, jm = 0;
            if (j >= 1) { jd = div14(j - 1); jm = (j - 1) - jd * 14; }
            bool jcls = (j == 0), jpad = (j > 196);
#pragma unroll
            for (int rg = 0; rg < 4; ++rg) {
                int row = lq*4 + rg;
                int tv, th;
                if (irow[rg] == 0 || jcls) { tv = 0; th = 32; }
                else { tv = (int)jd - giv[rg] + 15; th = 32 + (int)jm - gih[rg] + 15; }
                float s = (acc[ct][rg] + WS[w][row*64 + tv] + WS[w][row*64 + th]) * 0.125f;
                if (jpad) s = -1e30f;
                acc[ct][rg] = s;
            }
        }

        float mx[4], sm[4];
#pragma unroll
        for (int rg = 0; rg < 4; ++rg) {
            float m = acc[0][rg];
#pragma unroll
            for (int ct = 1; ct < 13; ++ct) m = fmaxf(m, acc[ct][rg]);
            m = fmaxf(m, __shfl_xor(m, 1)); m = fmaxf(m, __shfl_xor(m, 2));
            m = fmaxf(m, __shfl_xor(m, 4)); m = fmaxf(m, __shfl_xor(m, 8));
            mx[rg] = m;
        }
#pragma unroll
        for (int rg = 0; rg < 4; ++rg) {
            float s = 0.f;
#pragma unroll
            for (int ct = 0; ct < 13; ++ct) {
                float p = __expf(acc[ct][rg] - mx[rg]);
                acc[ct][rg] = p; s += p;
            }
            s += __shfl_xor(s, 1); s += __shfl_xor(s, 2);
            s += __shfl_xor(s, 4); s += __shfl_xor(s, 8);
            sm[rg] = 1.f / s;
        }

        float a0v[4];
#pragma unroll
        for (int ct = 0; ct < 13; ++ct) {
            int j = ct*16 + lr;
#pragma unroll
            for (int rg = 0; rg < 4; ++rg) {
                float a = acc[ct][rg] * sm[rg];
                Al[w][(lq*4 + rg) * SAL + j] = (f16)a;
                if (ct == 0) a0v[rg] = a;
            }
        }
        wfence();

        // ---- group-sum GEMM ----
        f32x4 gacc[2];
#pragma unroll
        for (int ct = 0; ct < 2; ++ct) { gacc[ct][0]=0.f; gacc[ct][1]=0.f; gacc[ct][2]=0.f; gacc[ct][3]=0.f; }
#pragma unroll
        for (int kc = 0; kc < 7; ++kc) {
            f16x8 af = *(f16x8*)&Al[w][lr * SAL + kc*32 + lq*8];
#pragma unroll
            for (int ct = 0; ct < 2; ++ct) {
                f16x8 bf = *(f16x8*)&Gt[(ct*16 + lr) * SGT + kc*32 + lq*8];
                gacc[ct] = __builtin_amdgcn_mfma_f32_16x16x32_f16(af, bf, gacc[ct], 0, 0, 0);
            }
        }

#pragma unroll
        for (int z = 0; z < 4; ++z) {
            f32x4 zz; zz[0]=0.f; zz[1]=0.f; zz[2]=0.f; zz[3]=0.f;
            *(f32x4*)&WS[w][z*256 + l*4] = zz;
        }
        wfence();
#pragma unroll
        for (int rg = 0; rg < 4; ++rg) {
            int row = lq*4 + rg;
            int g = lr;
            int tv, th;
            if (irow[rg] == 0) { tv = 0; th = 30; }
            else { tv = g - giv[rg] + 15; th = 30 + g - gih[rg] + 15; }
            atomicAdd(&WS[w][row*64 + tv], gacc[0][rg]);
            atomicAdd(&WS[w][row*64 + th], gacc[1][rg]);
        }
        if (lr == 0) {
#pragma unroll
            for (int rg = 0; rg < 4; ++rg) {
                int row = lq*4 + rg;
                atomicAdd(&WS[w][row*64 + 0],  a0v[rg]);
                atomicAdd(&WS[w][row*64 + 30], a0v[rg]);
            }
        }
        wfence();

#pragma unroll
        for (int u = 0; u < 4; ++u) {
            int r = u*4 + lq, c = lr * 4;
            float4 f = *(float4*)&WS[w][r*64 + c];
            f16x4 hv; hv[0]=(f16)f.x; hv[1]=(f16)f.y; hv[2]=(f16)f.z; hv[3]=(f16)f.w;
            *(f16x4*)&Al[w][r * SAL + 208 + c] = hv;
        }
        wfence();

        // ---- PV GEMM ----
        f32x4 oacc[4];
#pragma unroll
        for (int ct = 0; ct < 4; ++ct) { oacc[ct][0]=0.f; oacc[ct][1]=0.f; oacc[ct][2]=0.f; oacc[ct][3]=0.f; }
#pragma unroll
        for (int kc = 0; kc < 9; ++kc) {
            f16x8 af = *(f16x8*)&Al[w][lr * SAL + kc*32 + lq*8];
#pragma unroll
            for (int ct = 0; ct < 4; ++ct) {
                f16x8 bf = *(f16x8*)&Vt[(ct*16 + lr) * SVT + kc*32 + lq*8];
                oacc[ct] = __builtin_amdgcn_mfma_f32_16x16x32_f16(af, bf, oacc[ct], 0, 0, 0);
            }
        }

#pragma unroll
        for (int ct = 0; ct < 4; ++ct)
#pragma unroll
            for (int rg = 0; rg < 4; ++rg) {
                int i = i0 + lq*4 + rg;
                if (i < NTOK) {
                    int d = ct*16 + lr;
                    o_ws[((size_t)(b * NTOK + i) * NH + h) * HDIM + d] = (f16)oacc[ct][rg];
                }
            }
    }
}

extern "C" void kernel_launch(void* const* d_in, const int* in_sizes, int n_in,
                              void* d_out, int out_size, void* d_ws, size_t ws_size,
                              hipStream_t stream)
{
    const float* x     = (const float*)d_in[0];
    const float* wq    = (const float*)d_in[1];
    const float* wk    = (const float*)d_in[2];
    const float* wv    = (const float*)d_in[3];
    const float* wproj = (const float*)d_in[4];
    const float* bproj = (const float*)d_in[5];
    const float* rkv   = (const float*)d_in[6];
    const float* rkh   = (const float*)d_in[7];
    const float* rvv   = (const float*)d_in[8];
    const float* rvh   = (const float*)d_in[9];

    f16* ws = (f16*)d_ws;
    const size_t sz = (size_t)MROWS * EDIM;        // 9,682,944
    f16* xh    = ws;
    f16* qh    = xh + sz;
    f16* kh    = qh + sz;
    f16* vh    = kh + sz;
    f16* oh    = vh + sz;
    f16* wqkvT = oh + sz;                          // 2304*768
    f16* wpT   = wqkvT + (size_t)3*EDIM*EDIM;      // 768*768

    convert_x  <<<4728, 256, 0, stream>>>(x, xh);
    transpose_w<<<dim3(288, 4), 256, 0, stream>>>(wq, wk, wv, wproj, wqkvT, wpT);
    gemm_h     <<<dim3(18, 99), 256, 0, stream>>>(xh, wqkvT, qh, kh, vh,
                                                  nullptr, nullptr, 0);
    attn_mfma  <<<NB * NH, 256, 0, stream>>>(qh, kh, vh,
                                             rkv, rkh, rvv, rvh, oh);
    gemm_h     <<<dim3(6, 99), 256, 0, stream>>>(oh, wpT, nullptr, nullptr, nullptr,
                                                 (float*)d_out, bproj, 1);
}

// Round 5
// 198.793 us; speedup vs baseline: 14.3633x; 1.2961x over previous
//
#include <hip/hip_runtime.h>
#include <math.h>

typedef _Float16 f16;
typedef __attribute__((ext_vector_type(8))) _Float16 f16x8;
typedef __attribute__((ext_vector_type(4))) _Float16 f16x4;
typedef __attribute__((ext_vector_type(4))) float f32x4;

#define NH 12
#define HDIM 64
#define NTOK 197
#define EDIM 768
#define NB 64
#define MROWS (NB*NTOK)   // 12608

// ---------------------------------------------------------------------------
// x [12608x768] f32 -> f16.
// ---------------------------------------------------------------------------
__global__ __launch_bounds__(256) void convert_x(
    const float* __restrict__ x, f16* __restrict__ xh)
{
    int idx = blockIdx.x * 256 + threadIdx.x;
    const float4* s = (const float4*)x + (size_t)idx * 2;
    float4 a = s[0], b = s[1];
    f16x8 h;
    h[0]=(f16)a.x; h[1]=(f16)a.y; h[2]=(f16)a.z; h[3]=(f16)a.w;
    h[4]=(f16)b.x; h[5]=(f16)b.y; h[6]=(f16)b.z; h[7]=(f16)b.w;
    *(f16x8*)(xh + (size_t)idx * 8) = h;
}

// ---------------------------------------------------------------------------
// Transpose + f16-ify weights: wT[n][k] = w[k][n].
// ---------------------------------------------------------------------------
__global__ __launch_bounds__(256) void transpose_w(
    const float* __restrict__ wq, const float* __restrict__ wk,
    const float* __restrict__ wv, const float* __restrict__ wp,
    f16* __restrict__ wqkvT, f16* __restrict__ wpT)
{
    int m = blockIdx.y;
    const float* src = (m==0)?wq:(m==1)?wk:(m==2)?wv:wp;
    int idx = blockIdx.x * 256 + threadIdx.x;
    int n = idx / 96, kc = (idx - n * 96) * 8;
    f16x8 h;
#pragma unroll
    for (int e = 0; e < 8; ++e) h[e] = (f16)src[(size_t)(kc+e)*EDIM + n];
    f16* dst = (m < 3) ? (wqkvT + ((size_t)m*EDIM + n)*EDIM + kc)
                       : (wpT   + (size_t)n*EDIM + kc);
    *(f16x8*)dst = h;
}

// ---------------------------------------------------------------------------
// f16 MFMA GEMM (unchanged from round 4).
// ---------------------------------------------------------------------------
__global__ __launch_bounds__(256) void gemm_h(
    const f16* __restrict__ A, const f16* __restrict__ Bt,
    f16* __restrict__ q_o, f16* __restrict__ k_o, f16* __restrict__ v_o,
    float* __restrict__ p_o, const float* __restrict__ bias, int mode)
{
    __shared__ f16 As[128*64];
    __shared__ f16 Bs[128*64];

    const int tid = threadIdx.x;
    const int l  = tid & 63;
    const int w  = tid >> 6;
    const int lr = l & 15, lq = l >> 4;
    const int wr = w >> 1, wc = w & 1;
    const int m0 = blockIdx.y * 128, n0 = blockIdx.x * 128;

    const int sr = tid >> 3, sc = (tid & 7) << 3;
    const int sw = (sr & 7) << 3;
    const int dsoff = sr * 64 + (sc ^ sw);

    const f16* agp[4]; const f16* bgp[4];
#pragma unroll
    for (int p = 0; p < 4; ++p) {
        int ra = m0 + p*32 + sr; if (ra >= MROWS) ra = MROWS - 1;
        agp[p] = A  + (size_t)ra * EDIM + sc;
        bgp[p] = Bt + (size_t)(n0 + p*32 + sr) * EDIM + sc;
    }

    f16x8 ar_[4], br_[4];
#pragma unroll
    for (int p = 0; p < 4; ++p) {
        ar_[p] = *(const f16x8*)agp[p];
        br_[p] = *(const f16x8*)bgp[p];
    }

    f32x4 acc[4][4];
#pragma unroll
    for (int mt = 0; mt < 4; ++mt)
#pragma unroll
        for (int nt = 0; nt < 4; ++nt) {
            acc[mt][nt][0]=0.f; acc[mt][nt][1]=0.f;
            acc[mt][nt][2]=0.f; acc[mt][nt][3]=0.f;
        }

    for (int kt = 0; kt < 12; ++kt) {
        __syncthreads();
#pragma unroll
        for (int p = 0; p < 4; ++p) {
            *(f16x8*)&As[p*2048 + dsoff] = ar_[p];
            *(f16x8*)&Bs[p*2048 + dsoff] = br_[p];
        }
        if (kt < 11) {
            int ko = (kt + 1) * 64;
#pragma unroll
            for (int p = 0; p < 4; ++p) {
                ar_[p] = *(const f16x8*)(agp[p] + ko);
                br_[p] = *(const f16x8*)(bgp[p] + ko);
            }
        }
        __syncthreads();
#pragma unroll
        for (int ks = 0; ks < 2; ++ks) {
            const int kb = ks*32 + lq*8;
            f16x8 af[4], bf[4];
#pragma unroll
            for (int mt = 0; mt < 4; ++mt) {
                int Ra = wr*64 + mt*16 + lr;
                af[mt] = *(const f16x8*)&As[Ra*64 + (kb ^ ((Ra&7)<<3))];
                int Rb = wc*64 + mt*16 + lr;
                bf[mt] = *(const f16x8*)&Bs[Rb*64 + (kb ^ ((Rb&7)<<3))];
            }
#pragma unroll
            for (int mt = 0; mt < 4; ++mt)
#pragma unroll
                for (int nt = 0; nt < 4; ++nt)
                    acc[mt][nt] = __builtin_amdgcn_mfma_f32_16x16x32_f16(
                        af[mt], bf[nt], acc[mt][nt], 0, 0, 0);
        }
    }

    if (mode == 0) {
        const int mat   = n0 / EDIM;
        const int hbase = ((n0 % EDIM) >> 6) + wc;
        f16* dst = (mat == 0) ? q_o : (mat == 1) ? k_o : v_o;
#pragma unroll
        for (int mt = 0; mt < 4; ++mt)
#pragma unroll
            for (int rg = 0; rg < 4; ++rg) {
                int R = m0 + wr*64 + mt*16 + lq*4 + rg;
                if (R < MROWS) {
                    int bb = R / NTOK, nn = R - bb * NTOK;
                    f16* base = dst + (((size_t)(bb*NH + hbase))*NTOK + nn) * HDIM;
#pragma unroll
                    for (int nt = 0; nt < 4; ++nt)
                        base[nt*16 + lr] = (f16)acc[mt][nt][rg];
                }
            }
    } else {
#pragma unroll
        for (int mt = 0; mt < 4; ++mt)
#pragma unroll
            for (int rg = 0; rg < 4; ++rg) {
                int R = m0 + wr*64 + mt*16 + lq*4 + rg;
                if (R < MROWS) {
                    float* base = p_o + (size_t)R * EDIM + n0 + wc*64;
#pragma unroll
                    for (int nt = 0; nt < 4; ++nt) {
                        int c = nt*16 + lr;
                        base[c] = acc[mt][nt][rg] + bias[n0 + wc*64 + c];
                    }
                }
            }
    }
}

// ---------------------------------------------------------------------------
// MFMA fused attention, swapped-operand + in-register A design.
// One block per (b,h), 8 waves, wave owns a 16-query tile (13 tiles).
// All LDS tiles XOR-swizzled: f16 col ^= ((row&7)<<3), conflict-free b128.
//   Kl[272][64] : 0-196 K, 208+t rk_v, 240+t rk_h (else 0)
//   Vt[64][320] : Vt[d][k]: k<197 V[k][d]; 208+t rv_v; 238+t rv_h (else 0)
//   Gt[32][256] : Gt[g][j]=1 iff (j-1)/14==g (g<14); Gt[16+c][j]=1 iff (j-1)%14==c
//   WS[wave][16][68] f32: rows = query (i-local); P table then S' scatter
// S|P GEMM computes C[j,i] = K_ext . Q^T  (query = lane&15).
// ---------------------------------------------------------------------------
#define SKL 64
#define SVT 320
#define SGT 256
#define WSJ 68

__device__ __forceinline__ void wfence() {
    asm volatile("s_waitcnt lgkmcnt(0)" ::: "memory");
    __builtin_amdgcn_sched_barrier(0);
    __builtin_amdgcn_wave_barrier();
}

__device__ __forceinline__ unsigned div14(unsigned n) { return (n * 4682u) >> 16; }  // exact n<=206

__global__ __launch_bounds__(512, 2) void attn_mfma(
    const f16* __restrict__ q_ws, const f16* __restrict__ k_ws,
    const f16* __restrict__ v_ws,
    const float* __restrict__ rkv, const float* __restrict__ rkh,
    const float* __restrict__ rvv, const float* __restrict__ rvh,
    f16* __restrict__ o_ws)
{
    __shared__ f16 Kl[272*SKL];      // 34816 B
    __shared__ f16 Vt[64*SVT];       // 40960 B
    __shared__ f16 Gt[32*SGT];       // 16384 B
    __shared__ float WS[8][16*WSJ];  // 34816 B   total 126976 B

    const int tid = threadIdx.x;
    const int w = tid >> 6, l = tid & 63;
    const int lr = l & 15, lq = l >> 4;
    const int bh = blockIdx.x;
    const int b = bh / NH, h = bh - b * NH;
    const f16* Qp = q_ws + (size_t)bh * NTOK * HDIM;
    const f16* Kp = k_ws + (size_t)bh * NTOK * HDIM;
    const f16* Vp = v_ws + (size_t)bh * NTOK * HDIM;
    float* wsw = &WS[w][0];

    // ---- stage K_ext (row-major, XOR-swizzled cols) ----
    for (int idx = tid; idx < 272*8; idx += 512) {
        int row = idx >> 3, q8 = (idx & 7) << 3;
        f16x8 hv;
#pragma unroll
        for (int e = 0; e < 8; ++e) hv[e] = (f16)0.f;
        if (row < NTOK) {
            hv = *(const f16x8*)(Kp + row * 64 + q8);
        } else if (row >= 208 && row < 238) {
            const float* src = rkv + (row - 208) * 64 + q8;
            float4 a = *(const float4*)src, c = *(const float4*)(src + 4);
            hv[0]=(f16)a.x; hv[1]=(f16)a.y; hv[2]=(f16)a.z; hv[3]=(f16)a.w;
            hv[4]=(f16)c.x; hv[5]=(f16)c.y; hv[6]=(f16)c.z; hv[7]=(f16)c.w;
        } else if (row >= 240 && row < 270) {
            const float* src = rkh + (row - 240) * 64 + q8;
            float4 a = *(const float4*)src, c = *(const float4*)(src + 4);
            hv[0]=(f16)a.x; hv[1]=(f16)a.y; hv[2]=(f16)a.z; hv[3]=(f16)a.w;
            hv[4]=(f16)c.x; hv[5]=(f16)c.y; hv[6]=(f16)c.z; hv[7]=(f16)c.w;
        }
        *(f16x8*)&Kl[row * SKL + (q8 ^ ((row & 7) << 3))] = hv;
    }
    // ---- stage Vt (transpose; coalesced read, swizzled scalar writes) ----
    for (int idx = tid; idx < 288*8; idx += 512) {
        int k = idx >> 3, d8 = (idx & 7) << 3;
        f16 tv8[8];
#pragma unroll
        for (int e = 0; e < 8; ++e) tv8[e] = (f16)0.f;
        if (k < NTOK) {
            f16x8 vv = *(const f16x8*)(Vp + k * 64 + d8);
#pragma unroll
            for (int e = 0; e < 8; ++e) tv8[e] = vv[e];
        } else if (k >= 208 && k < 268) {
            const float* src = (k < 238) ? (rvv + (k - 208) * 64 + d8)
                                         : (rvh + (k - 238) * 64 + d8);
            float4 a = *(const float4*)src, c = *(const float4*)(src + 4);
            tv8[0]=(f16)a.x; tv8[1]=(f16)a.y; tv8[2]=(f16)a.z; tv8[3]=(f16)a.w;
            tv8[4]=(f16)c.x; tv8[5]=(f16)c.y; tv8[6]=(f16)c.z; tv8[7]=(f16)c.w;
        }
#pragma unroll
        for (int e = 0; e < 8; ++e) {
            int d = d8 + e;
            Vt[d * SVT + (k ^ ((d & 7) << 3))] = tv8[e];
        }
    }
    // ---- stage Gt ----
    for (int idx = tid; idx < 32*224; idx += 512) {
        int r = idx / 224, j = idx - r * 224;
        f16 g = (f16)0.f;
        if (j >= 1 && j <= 196) {
            unsigned jd = div14(j - 1), jm = (j - 1) - jd * 14;
            if (r < 14 && (int)jd == r) g = (f16)1.f;
            else if (r >= 16 && r < 30 && (int)jm == r - 16) g = (f16)1.f;
        }
        Gt[r * SGT + (j ^ ((r & 7) << 3))] = g;
    }
    __syncthreads();

    const int src0 = ((l >> 4) & 1) * 32 + lr;   // lane holding quads 2*(lq&1)
    const int src1 = src0 + 16;

    for (int tt = w; tt < 13; tt += 8) {
        const int i0 = tt * 16;
        const int iq = i0 + lr;                      // this lane's query
        const int iqc = (iq > 196) ? 196 : iq;       // clamped for Q load
        // Q as B-operand: lane holds col=lr (query), k = lq*8+e
        const f16* qsrc = Qp + iqc * 64 + lq * 8;
        f16x8 qf0 = *(const f16x8*)qsrc;
        f16x8 qf1 = *(const f16x8*)(qsrc + 32);

        // ---- S|P GEMM: C[j,i] over 17 j-tiles ----
        f32x4 acc[17];
        __builtin_amdgcn_s_setprio(1);
#pragma unroll
        for (int ct = 0; ct < 17; ++ct) {
            f32x4 a; a[0]=0.f; a[1]=0.f; a[2]=0.f; a[3]=0.f;
            const int krow = ct*16 + lr;
            const int swz = (lr & 7) << 3;
            f16x8 kf0 = *(f16x8*)&Kl[krow * SKL + ((lq*8) ^ swz)];
            f16x8 kf1 = *(f16x8*)&Kl[krow * SKL + ((32 + lq*8) ^ swz)];
            a = __builtin_amdgcn_mfma_f32_16x16x32_f16(kf0, qf0, a, 0, 0, 0);
            a = __builtin_amdgcn_mfma_f32_16x16x32_f16(kf1, qf1, a, 0, 0, 0);
            acc[ct] = a;
        }
        __builtin_amdgcn_s_setprio(0);

        // ---- store P table: WS[i=lr][toff] ----
#pragma unroll
        for (int ct = 13; ct < 17; ++ct)
#pragma unroll
            for (int rg = 0; rg < 4; ++rg) {
                int toff = (ct - 13)*16 + lq*4 + rg;
                wsw[lr * WSJ + toff] = acc[ct][rg];
            }
        wfence();

        // per-lane query rel-pos info
        int id_ = 0, ih_ = 0;
        const bool qcls = (iq == 0);
        if (iq > 0) { unsigned v = div14(iq - 1); id_ = (int)v; ih_ = (iq - 1) - (int)v * 14; }

        // ---- rel-key epilogue + mask ----
#pragma unroll
        for (int ct = 0; ct < 13; ++ct)
#pragma unroll
            for (int rg = 0; rg < 4; ++rg) {
                int j = ct*16 + lq*4 + rg;
                int tv, th;
                if (qcls || j == 0) { tv = 0; th = 32; }
                else {
                    unsigned jd = div14(j - 1), jm = (j - 1) - jd * 14;
                    tv = (int)jd - id_ + 15;
                    th = 32 + (int)jm - ih_ + 15;
                }
                float s = (acc[ct][rg] + wsw[lr*WSJ + tv] + wsw[lr*WSJ + th]) * 0.125f;
                if (j > 196) s = -1e30f;
                acc[ct][rg] = s;
            }

        // ---- softmax over j (in-lane chain + xor16/32) ----
        float m = -1e30f;
#pragma unroll
        for (int ct = 0; ct < 13; ++ct)
#pragma unroll
            for (int rg = 0; rg < 4; ++rg) m = fmaxf(m, acc[ct][rg]);
        m = fmaxf(m, __shfl_xor(m, 16));
        m = fmaxf(m, __shfl_xor(m, 32));
        float ssum = 0.f;
#pragma unroll
        for (int ct = 0; ct < 13; ++ct)
#pragma unroll
            for (int rg = 0; rg < 4; ++rg) {
                float p = __expf(acc[ct][rg] - m);
                acc[ct][rg] = p; ssum += p;
            }
        ssum += __shfl_xor(ssum, 16);
        ssum += __shfl_xor(ssum, 32);
        const float inv = 1.f / ssum;
        const float pn00 = acc[0][0] * inv;   // A[j=0, i] on lq==0 lanes

        // ---- pack normalized probs: pk[ct] = 4 rows as 2 u32 ----
        unsigned pk[13][2];
#pragma unroll
        for (int ct = 0; ct < 13; ++ct) {
            union { f16x4 h; unsigned u[2]; } t;
            t.h[0] = (f16)(acc[ct][0] * inv);
            t.h[1] = (f16)(acc[ct][1] * inv);
            t.h[2] = (f16)(acc[ct][2] * inv);
            t.h[3] = (f16)(acc[ct][3] * inv);
            pk[ct][0] = t.u[0]; pk[ct][1] = t.u[1];
        }

        // ---- redistribute to A-fragments: pa[kc], k = kc*32+lq*8+e ----
        f16x8 pa[7];
#pragma unroll
        for (int kc = 0; kc < 7; ++kc) {
            const int ctA = 2*kc;
            const int ctB = (kc == 6) ? 12 : 2*kc + 1;   // kc=6 hi -> zero
            unsigned A0 = (unsigned)__shfl((int)pk[ctA][0], src0);
            unsigned A1 = (unsigned)__shfl((int)pk[ctA][1], src0);
            unsigned A2 = (unsigned)__shfl((int)pk[ctA][0], src1);
            unsigned A3 = (unsigned)__shfl((int)pk[ctA][1], src1);
            unsigned B0 = (unsigned)__shfl((int)pk[ctB][0], src0);
            unsigned B1 = (unsigned)__shfl((int)pk[ctB][1], src0);
            unsigned B2 = (unsigned)__shfl((int)pk[ctB][0], src1);
            unsigned B3 = (unsigned)__shfl((int)pk[ctB][1], src1);
            bool hiHalf = (lq >= 2);
            union { unsigned u[4]; f16x8 v; } f;
            f.u[0] = hiHalf ? B0 : A0;
            f.u[1] = hiHalf ? B1 : A1;
            f.u[2] = hiHalf ? B2 : A2;
            f.u[3] = hiHalf ? B3 : A3;
            if (kc == 6 && hiHalf) { f.u[0]=0; f.u[1]=0; f.u[2]=0; f.u[3]=0; }
            pa[kc] = f.v;
        }

        // ---- group-sum GEMM: Sv (g=lane 0..13) | Sh (tile 1) ----
        f32x4 gacc[2];
#pragma unroll
        for (int ct = 0; ct < 2; ++ct) { gacc[ct][0]=0.f; gacc[ct][1]=0.f; gacc[ct][2]=0.f; gacc[ct][3]=0.f; }
        __builtin_amdgcn_s_setprio(1);
#pragma unroll
        for (int kc = 0; kc < 7; ++kc) {
            const int swz = (lr & 7) << 3;
#pragma unroll
            for (int ct = 0; ct < 2; ++ct) {
                f16x8 gf = *(f16x8*)&Gt[(ct*16 + lr) * SGT + ((kc*32 + lq*8) ^ swz)];
                gacc[ct] = __builtin_amdgcn_mfma_f32_16x16x32_f16(pa[kc], gf, gacc[ct], 0, 0, 0);
            }
        }
        __builtin_amdgcn_s_setprio(0);

        // ---- zero S' region, scatter group sums ----
        for (int z = l; z < 16*64; z += 64)
            wsw[(z >> 6) * WSJ + (z & 63)] = 0.f;
        wfence();
#pragma unroll
        for (int rg = 0; rg < 4; ++rg) {
            int il = lq*4 + rg;
            int iqs = i0 + il;
            float sv = gacc[0][rg], sh = gacc[1][rg];
            if (iqs == 0) {
                atomicAdd(&wsw[il*WSJ + 0],  sv);
                atomicAdd(&wsw[il*WSJ + 30], sh);
            } else {
                unsigned v = div14(iqs - 1);
                int id2 = (int)v, ih2 = (iqs - 1) - (int)v * 14;
                wsw[il*WSJ + (lr - id2 + 15)]      = sv;
                wsw[il*WSJ + 30 + (lr - ih2 + 15)] = sh;
            }
        }
        wfence();
        if (lq == 0) {   // CLS column j=0: A[i=lr,0] -> cols 0 and 30
            atomicAdd(&wsw[lr*WSJ + 0],  pn00);
            atomicAdd(&wsw[lr*WSJ + 30], pn00);
        }
        wfence();

        // ---- S' -> A-fragments (rows = i = lr) ----
        f16x8 sfr[2];
#pragma unroll
        for (int kc2 = 0; kc2 < 2; ++kc2) {
            f32x4 lo = *(f32x4*)&wsw[lr*WSJ + kc2*32 + lq*8];
            f32x4 hi = *(f32x4*)&wsw[lr*WSJ + kc2*32 + lq*8 + 4];
            f16x8 t;
            t[0]=(f16)lo[0]; t[1]=(f16)lo[1]; t[2]=(f16)lo[2]; t[3]=(f16)lo[3];
            t[4]=(f16)hi[0]; t[5]=(f16)hi[1]; t[6]=(f16)hi[2]; t[7]=(f16)hi[3];
            sfr[kc2] = t;
        }

        // ---- PV GEMM: O[i,d] = A_ext . V_ext ----
        f32x4 oacc[4];
#pragma unroll
        for (int ct = 0; ct < 4; ++ct) { oacc[ct][0]=0.f; oacc[ct][1]=0.f; oacc[ct][2]=0.f; oacc[ct][3]=0.f; }
        __builtin_amdgcn_s_setprio(1);
#pragma unroll
        for (int kc = 0; kc < 7; ++kc) {
            const int swz = (lr & 7) << 3;
#pragma unroll
            for (int ct = 0; ct < 4; ++ct) {
                f16x8 vf = *(f16x8*)&Vt[(ct*16 + lr) * SVT + ((kc*32 + lq*8) ^ swz)];
                oacc[ct] = __builtin_amdgcn_mfma_f32_16x16x32_f16(pa[kc], vf, oacc[ct], 0, 0, 0);
            }
        }
#pragma unroll
        for (int kc2 = 0; kc2 < 2; ++kc2) {
            const int swz = (lr & 7) << 3;
#pragma unroll
            for (int ct = 0; ct < 4; ++ct) {
                f16x8 vf = *(f16x8*)&Vt[(ct*16 + lr) * SVT + ((208 + kc2*32 + lq*8) ^ swz)];
                oacc[ct] = __builtin_amdgcn_mfma_f32_16x16x32_f16(sfr[kc2], vf, oacc[ct], 0, 0, 0);
            }
        }
        __builtin_amdgcn_s_setprio(0);

        // ---- store O: [B, N, H*HD]; C[r=i_local, c=d_local] ----
#pragma unroll
        for (int ct = 0; ct < 4; ++ct)
#pragma unroll
            for (int rg = 0; rg < 4; ++rg) {
                int io = i0 + lq*4 + rg;
                if (io < NTOK) {
                    int d = ct*16 + lr;
                    o_ws[((size_t)(b * NTOK + io) * NH + h) * HDIM + d] = (f16)oacc[ct][rg];
                }
            }
    }
}

extern "C" void kernel_launch(void* const* d_in, const int* in_sizes, int n_in,
                              void* d_out, int out_size, void* d_ws, size_t ws_size,
                              hipStream_t stream)
{
    const float* x     = (const float*)d_in[0];
    const float* wq    = (const float*)d_in[1];
    const float* wk    = (const float*)d_in[2];
    const float* wv    = (const float*)d_in[3];
    const float* wproj = (const float*)d_in[4];
    const float* bproj = (const float*)d_in[5];
    const float* rkv   = (const float*)d_in[6];
    const float* rkh   = (const float*)d_in[7];
    const float* rvv   = (const float*)d_in[8];
    const float* rvh   = (const float*)d_in[9];

    f16* ws = (f16*)d_ws;
    const size_t sz = (size_t)MROWS * EDIM;
    f16* xh    = ws;
    f16* qh    = xh + sz;
    f16* kh    = qh + sz;
    f16* vh    = kh + sz;
    f16* oh    = vh + sz;
    f16* wqkvT = oh + sz;
    f16* wpT   = wqkvT + (size_t)3*EDIM*EDIM;

    convert_x  <<<4728, 256, 0, stream>>>(x, xh);
    transpose_w<<<dim3(288, 4), 256, 0, stream>>>(wq, wk, wv, wproj, wqkvT, wpT);
    gemm_h     <<<dim3(18, 99), 256, 0, stream>>>(xh, wqkvT, qh, kh, vh,
                                                  nullptr, nullptr, 0);
    attn_mfma  <<<NB * NH, 512, 0, stream>>>(qh, kh, vh,
                                             rkv, rkh, rvv, rvh, oh);
    gemm_h     <<<dim3(6, 99), 256, 0, stream>>>(oh, wpT, nullptr, nullptr, nullptr,
                                                 (float*)d_out, bproj, 1);
}

// Round 6
// 177.429 us; speedup vs baseline: 16.0928x; 1.1204x over previous
//
#include <hip/hip_runtime.h>
#include <math.h>

typedef _Float16 f16;
typedef __attribute__((ext_vector_type(8))) _Float16 f16x8;
typedef __attribute__((ext_vector_type(4))) _Float16 f16x4;
typedef __attribute__((ext_vector_type(4))) float f32x4;

#define NH 12
#define HDIM 64
#define NTOK 197
#define EDIM 768
#define NB 64
#define MROWS (NB*NTOK)   // 12608

// ---------------------------------------------------------------------------
// x [12608x768] f32 -> f16.
// ---------------------------------------------------------------------------
__global__ __launch_bounds__(256) void convert_x(
    const float* __restrict__ x, f16* __restrict__ xh)
{
    int idx = blockIdx.x * 256 + threadIdx.x;
    const float4* s = (const float4*)x + (size_t)idx * 2;
    float4 a = s[0], b = s[1];
    f16x8 h;
    h[0]=(f16)a.x; h[1]=(f16)a.y; h[2]=(f16)a.z; h[3]=(f16)a.w;
    h[4]=(f16)b.x; h[5]=(f16)b.y; h[6]=(f16)b.z; h[7]=(f16)b.w;
    *(f16x8*)(xh + (size_t)idx * 8) = h;
}

// ---------------------------------------------------------------------------
// LDS-tiled transpose + f16: wT[n][k] = (f16)w[k][n].  64x64 f32 tiles.
// grid (12 k-tiles, 12 n-tiles, 4 matrices), 256 threads.
// ---------------------------------------------------------------------------
__global__ __launch_bounds__(256) void transpose_w(
    const float* __restrict__ wq, const float* __restrict__ wk,
    const float* __restrict__ wv, const float* __restrict__ wp,
    f16* __restrict__ wqkvT, f16* __restrict__ wpT)
{
    __shared__ float T[64][65];
    int m = blockIdx.z;
    const float* src = (m==0)?wq:(m==1)?wk:(m==2)?wv:wp;
    int k0 = blockIdx.x * 64, n0 = blockIdx.y * 64;
    int cidx = threadIdx.x & 63, r4 = threadIdx.x >> 6;
#pragma unroll
    for (int rr = 0; rr < 16; ++rr) {
        int kl = rr*4 + r4;
        T[kl][cidx] = src[(size_t)(k0+kl)*EDIM + n0 + cidx];
    }
    __syncthreads();
    f16* dst = (m < 3) ? (wqkvT + (size_t)m*EDIM*EDIM) : wpT;
#pragma unroll
    for (int rr = 0; rr < 16; ++rr) {
        int nl = rr*4 + r4;
        dst[(size_t)(n0+nl)*EDIM + k0 + cidx] = (f16)T[cidx][nl];
    }
}

// ---------------------------------------------------------------------------
// f16 MFMA GEMM (unchanged, proven).
// ---------------------------------------------------------------------------
__global__ __launch_bounds__(256) void gemm_h(
    const f16* __restrict__ A, const f16* __restrict__ Bt,
    f16* __restrict__ q_o, f16* __restrict__ k_o, f16* __restrict__ v_o,
    float* __restrict__ p_o, const float* __restrict__ bias, int mode)
{
    __shared__ f16 As[128*64];
    __shared__ f16 Bs[128*64];

    const int tid = threadIdx.x;
    const int l  = tid & 63;
    const int w  = tid >> 6;
    const int lr = l & 15, lq = l >> 4;
    const int wr = w >> 1, wc = w & 1;
    const int m0 = blockIdx.y * 128, n0 = blockIdx.x * 128;

    const int sr = tid >> 3, sc = (tid & 7) << 3;
    const int sw = (sr & 7) << 3;
    const int dsoff = sr * 64 + (sc ^ sw);

    const f16* agp[4]; const f16* bgp[4];
#pragma unroll
    for (int p = 0; p < 4; ++p) {
        int ra = m0 + p*32 + sr; if (ra >= MROWS) ra = MROWS - 1;
        agp[p] = A  + (size_t)ra * EDIM + sc;
        bgp[p] = Bt + (size_t)(n0 + p*32 + sr) * EDIM + sc;
    }

    f16x8 ar_[4], br_[4];
#pragma unroll
    for (int p = 0; p < 4; ++p) {
        ar_[p] = *(const f16x8*)agp[p];
        br_[p] = *(const f16x8*)bgp[p];
    }

    f32x4 acc[4][4];
#pragma unroll
    for (int mt = 0; mt < 4; ++mt)
#pragma unroll
        for (int nt = 0; nt < 4; ++nt) {
            acc[mt][nt][0]=0.f; acc[mt][nt][1]=0.f;
            acc[mt][nt][2]=0.f; acc[mt][nt][3]=0.f;
        }

    for (int kt = 0; kt < 12; ++kt) {
        __syncthreads();
#pragma unroll
        for (int p = 0; p < 4; ++p) {
            *(f16x8*)&As[p*2048 + dsoff] = ar_[p];
            *(f16x8*)&Bs[p*2048 + dsoff] = br_[p];
        }
        if (kt < 11) {
            int ko = (kt + 1) * 64;
#pragma unroll
            for (int p = 0; p < 4; ++p) {
                ar_[p] = *(const f16x8*)(agp[p] + ko);
                br_[p] = *(const f16x8*)(bgp[p] + ko);
            }
        }
        __syncthreads();
#pragma unroll
        for (int ks = 0; ks < 2; ++ks) {
            const int kb = ks*32 + lq*8;
            f16x8 af[4], bf[4];
#pragma unroll
            for (int mt = 0; mt < 4; ++mt) {
                int Ra = wr*64 + mt*16 + lr;
                af[mt] = *(const f16x8*)&As[Ra*64 + (kb ^ ((Ra&7)<<3))];
                int Rb = wc*64 + mt*16 + lr;
                bf[mt] = *(const f16x8*)&Bs[Rb*64 + (kb ^ ((Rb&7)<<3))];
            }
#pragma unroll
            for (int mt = 0; mt < 4; ++mt)
#pragma unroll
                for (int nt = 0; nt < 4; ++nt)
                    acc[mt][nt] = __builtin_amdgcn_mfma_f32_16x16x32_f16(
                        af[mt], bf[nt], acc[mt][nt], 0, 0, 0);
        }
    }

    if (mode == 0) {
        const int mat   = n0 / EDIM;
        const int hbase = ((n0 % EDIM) >> 6) + wc;
        f16* dst = (mat == 0) ? q_o : (mat == 1) ? k_o : v_o;
#pragma unroll
        for (int mt = 0; mt < 4; ++mt)
#pragma unroll
            for (int rg = 0; rg < 4; ++rg) {
                int R = m0 + wr*64 + mt*16 + lq*4 + rg;
                if (R < MROWS) {
                    int bb = R / NTOK, nn = R - bb * NTOK;
                    f16* base = dst + (((size_t)(bb*NH + hbase))*NTOK + nn) * HDIM;
#pragma unroll
                    for (int nt = 0; nt < 4; ++nt)
                        base[nt*16 + lr] = (f16)acc[mt][nt][rg];
                }
            }
    } else {
#pragma unroll
        for (int mt = 0; mt < 4; ++mt)
#pragma unroll
            for (int rg = 0; rg < 4; ++rg) {
                int R = m0 + wr*64 + mt*16 + lq*4 + rg;
                if (R < MROWS) {
                    float* base = p_o + (size_t)R * EDIM + n0 + wc*64;
#pragma unroll
                    for (int nt = 0; nt < 4; ++nt) {
                        int c = nt*16 + lr;
                        base[c] = acc[mt][nt][rg] + bias[n0 + wc*64 + c];
                    }
                }
            }
    }
}

// ---------------------------------------------------------------------------
// MFMA fused attention v3. One block per (b,h), 12 waves, wave w owns the
// 16-query tile w (wave 0 also does tile 12).
//
// Rel-key logits computed BY GEMM: Kle carries 32 extra columns holding the
// static one-hot Gt2[j][g] (g<14: v-group of j, 16+gh: h-group, j=0 -> slots
// 14/30); B-side gets Qcomb[g][i] = P_v/h(i, g - g?(i) + 15) built from the
// P-table with 8 scalar LDS reads per lane. S = K.q + Gt2.Qcomb (raw), scale
// folded into exp2.
//
// LDS (f16):
//   Kle[272][104]: cols 0-63 K_ext (0-196 K, 208+t rk_v, 240+t rk_h),
//                  cols 64-95 Gt2 (rows<208), cols 96-103 pad. pad-stride 52dw
//   Vt [64][320] : Vt[d][k ^ ((d&7)<<3)]; k<197 V, 208+t rv_v, 238+t rv_h
//   Gt [32][232] : group one-hot [g][j] for group-sum GEMM (pad-stride 116dw)
//   WSh[12][16][72]: per-wave scratch; P-table (cols 0-63) then S' (0-59)
// ---------------------------------------------------------------------------
#define SKE 104
#define SVT 320
#define SGT 232
#define SWS 72

__device__ __forceinline__ void wfence() {
    asm volatile("s_waitcnt lgkmcnt(0)" ::: "memory");
    __builtin_amdgcn_sched_barrier(0);
    __builtin_amdgcn_wave_barrier();
}

__device__ __forceinline__ unsigned div14(unsigned n) { return (n * 4682u) >> 16; }  // exact n<=206

__global__ __launch_bounds__(768, 1) void attn_mfma(
    const f16* __restrict__ q_ws, const f16* __restrict__ k_ws,
    const f16* __restrict__ v_ws,
    const float* __restrict__ rkv, const float* __restrict__ rkh,
    const float* __restrict__ rvv, const float* __restrict__ rvh,
    f16* __restrict__ o_ws)
{
    __shared__ f16 Kle[272*SKE];     // 56576 B
    __shared__ f16 Vt[64*SVT];       // 40960 B
    __shared__ f16 Gt[32*SGT];       // 14848 B
    __shared__ f16 WSh[12*16*SWS];   // 27648 B   total 140032 B

    const int tid = threadIdx.x;
    const int w = tid >> 6, l = tid & 63;
    const int lr = l & 15, lq = l >> 4;
    const int bh = blockIdx.x;
    const int b = bh / NH, h = bh - b * NH;
    const f16* Qp = q_ws + (size_t)bh * NTOK * HDIM;
    const f16* Kp = k_ws + (size_t)bh * NTOK * HDIM;
    const f16* Vp = v_ws + (size_t)bh * NTOK * HDIM;
    f16* wsh = &WSh[w * 16 * SWS];

    // ---- stage Kle (data cols + embedded Gt2) ----
    for (int idx = tid; idx < 272*13; idx += 768) {
        int row = idx / 13, c = idx - row*13;
        int c8 = c << 3;
        f16x8 hv;
#pragma unroll
        for (int e = 0; e < 8; ++e) hv[e] = (f16)0.f;
        if (c < 8) {
            if (row < NTOK) {
                hv = *(const f16x8*)(Kp + row*64 + c8);
            } else if (row >= 208 && row < 238) {
                const float* src = rkv + (row-208)*64 + c8;
                float4 a = *(const float4*)src, d = *(const float4*)(src+4);
                hv[0]=(f16)a.x; hv[1]=(f16)a.y; hv[2]=(f16)a.z; hv[3]=(f16)a.w;
                hv[4]=(f16)d.x; hv[5]=(f16)d.y; hv[6]=(f16)d.z; hv[7]=(f16)d.w;
            } else if (row >= 240 && row < 270) {
                const float* src = rkh + (row-240)*64 + c8;
                float4 a = *(const float4*)src, d = *(const float4*)(src+4);
                hv[0]=(f16)a.x; hv[1]=(f16)a.y; hv[2]=(f16)a.z; hv[3]=(f16)a.w;
                hv[4]=(f16)d.x; hv[5]=(f16)d.y; hv[6]=(f16)d.z; hv[7]=(f16)d.w;
            }
        } else if (c < 12 && row < 208) {
            int gbase = (c - 8) << 3;
            if (row == 0) {
#pragma unroll
                for (int e = 0; e < 8; ++e) {
                    int g = gbase + e;
                    hv[e] = (g == 14 || g == 30) ? (f16)1.f : (f16)0.f;
                }
            } else if (row <= 196) {
                int rm = row - 1;
                int gv = (int)div14((unsigned)rm);
                int gh = rm - gv*14;
#pragma unroll
                for (int e = 0; e < 8; ++e) {
                    int g = gbase + e;
                    hv[e] = (g == gv || g == 16 + gh) ? (f16)1.f : (f16)0.f;
                }
            }
        }
        *(f16x8*)&Kle[row*SKE + c8] = hv;
    }

    // ---- stage Vt: thread owns (dlow, k) so the swizzle key varies per lane
    //      -> conflict-free scalar writes ----
    for (int idx = tid; idx < 8*SVT; idx += 768) {
        int dlow = idx & 7, k = idx >> 3;
        int kx = k ^ (dlow << 3);
        bool isV = (k < NTOK), isA = (k >= 208 && k < 238), isB = (k >= 238 && k < 268);
#pragma unroll
        for (int e = 0; e < 8; ++e) {
            int d = (e << 3) + dlow;
            f16 val = (f16)0.f;
            if (isV)      val = Vp[k*64 + d];
            else if (isA) val = (f16)rvv[(k-208)*64 + d];
            else if (isB) val = (f16)rvh[(k-238)*64 + d];
            Vt[d*SVT + kx] = val;
        }
    }

    // ---- stage Gt [g][j] ----
    for (int idx = tid; idx < 32*29; idx += 768) {
        int g = idx / 29, c = idx - g*29, c8 = c << 3;
        f16x8 hv;
#pragma unroll
        for (int e = 0; e < 8; ++e) hv[e] = (f16)0.f;
        if (g < 14 || (g >= 16 && g < 30)) {
#pragma unroll
            for (int e = 0; e < 8; ++e) {
                int j = c8 + e;
                if (j >= 1 && j <= 196) {
                    int jm = j - 1;
                    int gv = (int)div14((unsigned)jm);
                    int gh = jm - gv*14;
                    if ((g < 14 && gv == g) || (g >= 16 && gh == g - 16))
                        hv[e] = (f16)1.f;
                }
            }
        }
        *(f16x8*)&Gt[g*SGT + c8] = hv;
    }
    __syncthreads();

    const int src0 = ((l >> 4) & 1) * 32 + lr;
    const int src1 = src0 + 16;

    for (int tt = w; tt < 13; tt += 12) {
        const int i0 = tt * 16;
        const int iq = i0 + lr;
        const int iqc = (iq > 196) ? 196 : iq;
        const f16* qsrc = Qp + iqc*64 + lq*8;
        f16x8 qf0 = *(const f16x8*)qsrc;
        f16x8 qf1 = *(const f16x8*)(qsrc + 32);

        // ---- P-pass: table dot products (rows 208-271) ----
        __builtin_amdgcn_s_setprio(1);
        f32x4 pacc[4];
#pragma unroll
        for (int ct = 0; ct < 4; ++ct) {
            f32x4 a; a[0]=0.f; a[1]=0.f; a[2]=0.f; a[3]=0.f;
            const int krow = (13+ct)*16 + lr;
            f16x8 kf0 = *(f16x8*)&Kle[krow*SKE + lq*8];
            f16x8 kf1 = *(f16x8*)&Kle[krow*SKE + 32 + lq*8];
            a = __builtin_amdgcn_mfma_f32_16x16x32_f16(kf0, qf0, a, 0, 0, 0);
            a = __builtin_amdgcn_mfma_f32_16x16x32_f16(kf1, qf1, a, 0, 0, 0);
            pacc[ct] = a;
        }
        __builtin_amdgcn_s_setprio(0);
#pragma unroll
        for (int ct = 0; ct < 4; ++ct)
#pragma unroll
            for (int rg = 0; rg < 4; ++rg)
                wsh[lr*SWS + ct*16 + lq*4 + rg] = (f16)pacc[ct][rg];
        wfence();

        // ---- Qcomb: per-lane shifted table (8 scalar LDS reads) ----
        int id_ = 0, ih_ = 0;
        const bool qcls = (iq == 0);
        if (iq > 0) { unsigned v = div14((unsigned)(iq-1)); id_ = (int)v; ih_ = (iq-1) - (int)v*14; }
        f16x8 qcf;
#pragma unroll
        for (int e = 0; e < 8; ++e) {
            int g = lq*8 + e;
            int toff;
            if (g < 14)       toff = qcls ? 0 : (g - id_ + 15);
            else if (g == 14) toff = 0;
            else if (g == 15) toff = 63;
            else if (g < 30)  toff = qcls ? 32 : (32 + (g-16) - ih_ + 15);
            else if (g == 30) toff = 32;
            else              toff = 63;
            qcf[e] = wsh[lr*SWS + toff];
        }

        // ---- S-pass: K.q + Gt2.Qcomb (raw logits) ----
        f32x4 acc[13];
        __builtin_amdgcn_s_setprio(1);
#pragma unroll
        for (int ct = 0; ct < 13; ++ct) {
            f32x4 a; a[0]=0.f; a[1]=0.f; a[2]=0.f; a[3]=0.f;
            const int krow = ct*16 + lr;
            f16x8 kf0 = *(f16x8*)&Kle[krow*SKE + lq*8];
            f16x8 kf1 = *(f16x8*)&Kle[krow*SKE + 32 + lq*8];
            f16x8 gf  = *(f16x8*)&Kle[krow*SKE + 64 + lq*8];
            a = __builtin_amdgcn_mfma_f32_16x16x32_f16(kf0, qf0, a, 0, 0, 0);
            a = __builtin_amdgcn_mfma_f32_16x16x32_f16(kf1, qf1, a, 0, 0, 0);
            a = __builtin_amdgcn_mfma_f32_16x16x32_f16(gf,  qcf, a, 0, 0, 0);
            acc[ct] = a;
        }
        __builtin_amdgcn_s_setprio(0);

        // mask padded j (tile 12 rows j>196)
#pragma unroll
        for (int rg = 0; rg < 4; ++rg)
            if (lq*4 + rg > 4) acc[12][rg] = -1e30f;

        // ---- softmax over j (scale folded into exp2) ----
        float m = -1e30f;
#pragma unroll
        for (int ct = 0; ct < 13; ++ct)
#pragma unroll
            for (int rg = 0; rg < 4; ++rg) m = fmaxf(m, acc[ct][rg]);
        m = fmaxf(m, __shfl_xor(m, 16));
        m = fmaxf(m, __shfl_xor(m, 32));
        const float C1 = 0.125f * 1.44269504088896f;
        const float nm = -m * C1;
        float ssum = 0.f;
#pragma unroll
        for (int ct = 0; ct < 13; ++ct)
#pragma unroll
            for (int rg = 0; rg < 4; ++rg) {
                float p = exp2f(fmaf(acc[ct][rg], C1, nm));
                acc[ct][rg] = p; ssum += p;
            }
        ssum += __shfl_xor(ssum, 16);
        ssum += __shfl_xor(ssum, 32);
        const float inv = 1.f / ssum;
        const float pn00 = acc[0][0] * inv;

        // ---- pack normalized probs ----
        unsigned pk[13][2];
#pragma unroll
        for (int ct = 0; ct < 13; ++ct) {
            union { f16x4 hh; unsigned u[2]; } t;
            t.hh[0] = (f16)(acc[ct][0] * inv);
            t.hh[1] = (f16)(acc[ct][1] * inv);
            t.hh[2] = (f16)(acc[ct][2] * inv);
            t.hh[3] = (f16)(acc[ct][3] * inv);
            pk[ct][0] = t.u[0]; pk[ct][1] = t.u[1];
        }

        // ---- redistribute to A-fragments ----
        f16x8 pa[7];
#pragma unroll
        for (int kc = 0; kc < 7; ++kc) {
            const int ctA = 2*kc;
            const int ctB = (kc == 6) ? 12 : 2*kc + 1;
            unsigned A0 = (unsigned)__shfl((int)pk[ctA][0], src0);
            unsigned A1 = (unsigned)__shfl((int)pk[ctA][1], src0);
            unsigned A2 = (unsigned)__shfl((int)pk[ctA][0], src1);
            unsigned A3 = (unsigned)__shfl((int)pk[ctA][1], src1);
            unsigned B0 = (unsigned)__shfl((int)pk[ctB][0], src0);
            unsigned B1 = (unsigned)__shfl((int)pk[ctB][1], src0);
            unsigned B2 = (unsigned)__shfl((int)pk[ctB][0], src1);
            unsigned B3 = (unsigned)__shfl((int)pk[ctB][1], src1);
            bool hiHalf = (lq >= 2);
            union { unsigned u[4]; f16x8 v; } f;
            f.u[0] = hiHalf ? B0 : A0;
            f.u[1] = hiHalf ? B1 : A1;
            f.u[2] = hiHalf ? B2 : A2;
            f.u[3] = hiHalf ? B3 : A3;
            if (kc == 6 && hiHalf) { f.u[0]=0; f.u[1]=0; f.u[2]=0; f.u[3]=0; }
            pa[kc] = f.v;
        }

        // ---- group-sum GEMM ----
        f32x4 gacc[2];
#pragma unroll
        for (int ct = 0; ct < 2; ++ct) { gacc[ct][0]=0.f; gacc[ct][1]=0.f; gacc[ct][2]=0.f; gacc[ct][3]=0.f; }
        __builtin_amdgcn_s_setprio(1);
#pragma unroll
        for (int kc = 0; kc < 7; ++kc) {
#pragma unroll
            for (int ct = 0; ct < 2; ++ct) {
                f16x8 gf = *(f16x8*)&Gt[(ct*16 + lr)*SGT + kc*32 + lq*8];
                gacc[ct] = __builtin_amdgcn_mfma_f32_16x16x32_f16(pa[kc], gf, gacc[ct], 0, 0, 0);
            }
        }
        __builtin_amdgcn_s_setprio(0);

        // ---- S' zero (cols 0-63), scatter (no atomics) ----
#pragma unroll
        for (int z = 0; z < 2; ++z) {
            int zi = z*64 + l;
            int zr = zi >> 3, zc = (zi & 7) << 3;
            f16x8 zz;
#pragma unroll
            for (int e = 0; e < 8; ++e) zz[e] = (f16)0.f;
            *(f16x8*)&wsh[zr*SWS + zc] = zz;
        }
        wfence();
#pragma unroll
        for (int rg = 0; rg < 4; ++rg) {
            int il = lq*4 + rg;
            int is_ = i0 + il;
            if (lr < 14 && is_ > 0) {
                unsigned v = div14((unsigned)(is_-1));
                int id2 = (int)v, ih2 = (is_-1) - (int)v*14;
                wsh[il*SWS + (lr - id2 + 15)]      = (f16)gacc[0][rg];
                wsh[il*SWS + 30 + (lr - ih2 + 15)] = (f16)gacc[1][rg];
            }
        }
        if (lq == 0 && !(i0 == 0 && lr == 0)) {
            wsh[lr*SWS + 0]  = (f16)pn00;
            wsh[lr*SWS + 30] = (f16)pn00;
        }
        if (i0 == 0) {   // CLS row: reduce group sums across g-lanes
            float sv = (lq == 0) ? gacc[0][0] : 0.f;
            float sh = (lq == 0) ? gacc[1][0] : 0.f;
            sv += __shfl_xor(sv, 1); sv += __shfl_xor(sv, 2);
            sv += __shfl_xor(sv, 4); sv += __shfl_xor(sv, 8);
            sh += __shfl_xor(sh, 1); sh += __shfl_xor(sh, 2);
            sh += __shfl_xor(sh, 4); sh += __shfl_xor(sh, 8);
            if (l == 0) {
                wsh[0]  = (f16)(sv + pn00);
                wsh[30] = (f16)(sh + pn00);
            }
        }
        wfence();

        // ---- S' -> A-fragments (f16 direct) ----
        f16x8 sfr[2];
#pragma unroll
        for (int kc2 = 0; kc2 < 2; ++kc2)
            sfr[kc2] = *(f16x8*)&wsh[lr*SWS + kc2*32 + lq*8];

        // ---- PV GEMM ----
        f32x4 oacc[4];
#pragma unroll
        for (int ct = 0; ct < 4; ++ct) { oacc[ct][0]=0.f; oacc[ct][1]=0.f; oacc[ct][2]=0.f; oacc[ct][3]=0.f; }
        __builtin_amdgcn_s_setprio(1);
        const int swz = (lr & 7) << 3;
#pragma unroll
        for (int kc = 0; kc < 7; ++kc) {
#pragma unroll
            for (int ct = 0; ct < 4; ++ct) {
                f16x8 vf = *(f16x8*)&Vt[(ct*16 + lr)*SVT + ((kc*32 + lq*8) ^ swz)];
                oacc[ct] = __builtin_amdgcn_mfma_f32_16x16x32_f16(pa[kc], vf, oacc[ct], 0, 0, 0);
            }
        }
#pragma unroll
        for (int kc2 = 0; kc2 < 2; ++kc2) {
#pragma unroll
            for (int ct = 0; ct < 4; ++ct) {
                f16x8 vf = *(f16x8*)&Vt[(ct*16 + lr)*SVT + ((208 + kc2*32 + lq*8) ^ swz)];
                oacc[ct] = __builtin_amdgcn_mfma_f32_16x16x32_f16(sfr[kc2], vf, oacc[ct], 0, 0, 0);
            }
        }
        __builtin_amdgcn_s_setprio(0);

        // ---- store O in [B, N, H*HD] ----
#pragma unroll
        for (int ct = 0; ct < 4; ++ct)
#pragma unroll
            for (int rg = 0; rg < 4; ++rg) {
                int io = i0 + lq*4 + rg;
                if (io < NTOK) {
                    int d = ct*16 + lr;
                    o_ws[((size_t)(b * NTOK + io) * NH + h) * HDIM + d] = (f16)oacc[ct][rg];
                }
            }
    }
}

extern "C" void kernel_launch(void* const* d_in, const int* in_sizes, int n_in,
                              void* d_out, int out_size, void* d_ws, size_t ws_size,
                              hipStream_t stream)
{
    const float* x     = (const float*)d_in[0];
    const float* wq    = (const float*)d_in[1];
    const float* wk    = (const float*)d_in[2];
    const float* wv    = (const float*)d_in[3];
    const float* wproj = (const float*)d_in[4];
    const float* bproj = (const float*)d_in[5];
    const float* rkv   = (const float*)d_in[6];
    const float* rkh   = (const float*)d_in[7];
    const float* rvv   = (const float*)d_in[8];
    const float* rvh   = (const float*)d_in[9];

    f16* ws = (f16*)d_ws;
    const size_t sz = (size_t)MROWS * EDIM;
    f16* xh    = ws;
    f16* qh    = xh + sz;
    f16* kh    = qh + sz;
    f16* vh    = kh + sz;
    f16* oh    = vh + sz;
    f16* wqkvT = oh + sz;
    f16* wpT   = wqkvT + (size_t)3*EDIM*EDIM;

    convert_x  <<<4728, 256, 0, stream>>>(x, xh);
    transpose_w<<<dim3(12, 12, 4), 256, 0, stream>>>(wq, wk, wv, wproj, wqkvT, wpT);
    gemm_h     <<<dim3(18, 99), 256, 0, stream>>>(xh, wqkvT, qh, kh, vh,
                                                  nullptr, nullptr, 0);
    attn_mfma  <<<NB * NH, 768, 0, stream>>>(qh, kh, vh,
                                             rkv, rkh, rvv, rvh, oh);
    gemm_h     <<<dim3(6, 99), 256, 0, stream>>>(oh, wpT, nullptr, nullptr, nullptr,
                                                 (float*)d_out, bproj, 1);
}